// Round 6
// baseline (206.564 us; speedup 1.0000x reference)
//
#include <hip/hip_runtime.h>
#include <math.h>

#define BN 8192      // B*N tokens
#define DIM 1024     // D
#define NE 8         // E experts
#define RR 256       // R

using bf16x8 = __attribute__((ext_vector_type(8))) short;
using f32x4  = __attribute__((ext_vector_type(4))) float;

#define GLD16(g, l) __builtin_amdgcn_global_load_lds(                      \
    (const __attribute__((address_space(1))) void*)(g),                    \
    (__attribute__((address_space(3))) void*)(l), 16, 0, 0)

__device__ inline unsigned short f2bf(float f) {
    unsigned int u = __float_as_uint(f);
    u = (u + 0x7fffu + ((u >> 16) & 1u)) >> 16;
    return (unsigned short)u;
}

// ------- routing (gw read in native [D][E] layout) + x->bf16 + counting -----
// One wave per token. Per-block aggregated expert counting via 8 shared
// counters -> one burst of <=8 global atomics per block (order-independent).
__global__ __launch_bounds__(256) void k_router3(const float* __restrict__ x,
                                                 const float* __restrict__ gw,
                                                 int* __restrict__ topi,
                                                 float* __restrict__ topw,
                                                 unsigned short* __restrict__ xb,
                                                 int* __restrict__ counts) {
    int wid  = (blockIdx.x * blockDim.x + threadIdx.x) >> 6;
    int lane = threadIdx.x & 63;
    const float* xp = x + (size_t)wid * DIM + lane * 4;
    unsigned short* xbp = xb + (size_t)wid * DIM + lane * 4;
    float lg[NE];
#pragma unroll
    for (int e = 0; e < NE; ++e) lg[e] = 0.f;
#pragma unroll
    for (int k = 0; k < 4; ++k) {
        float4 xv = *(const float4*)(xp + k * 256);
        ushort4 us = { f2bf(xv.x), f2bf(xv.y), f2bf(xv.z), f2bf(xv.w) };
        *(ushort4*)(xbp + k * 256) = us;
        const float* gp = gw + (size_t)(k * 256 + lane * 4) * NE;
#pragma unroll
        for (int j = 0; j < 4; ++j) {
            float xj = (j == 0) ? xv.x : (j == 1) ? xv.y : (j == 2) ? xv.z : xv.w;
            float4 g0 = *(const float4*)(gp + j * NE);
            float4 g1 = *(const float4*)(gp + j * NE + 4);
            lg[0] += xj * g0.x; lg[1] += xj * g0.y;
            lg[2] += xj * g0.z; lg[3] += xj * g0.w;
            lg[4] += xj * g1.x; lg[5] += xj * g1.y;
            lg[6] += xj * g1.z; lg[7] += xj * g1.w;
        }
    }
#pragma unroll
    for (int off = 32; off; off >>= 1) {
#pragma unroll
        for (int e = 0; e < NE; ++e) lg[e] += __shfl_xor(lg[e], off, 64);
    }
    __shared__ int bc[NE];
    if (threadIdx.x < NE) bc[threadIdx.x] = 0;
    __syncthreads();
    if (lane == 0) {
        float best = lg[0]; int bi = 0;
#pragma unroll
        for (int e = 1; e < NE; ++e) if (lg[e] > best) { best = lg[e]; bi = e; }
        float sec = -3.4e38f; int si = 0;
#pragma unroll
        for (int e = 0; e < NE; ++e) if (e != bi && lg[e] > sec) { sec = lg[e]; si = e; }
        float p  = __expf(sec - best);
        float w0 = 1.f / (1.f + p);
        float w1 = p * w0;
        topi[wid * 2 + 0] = bi;  topw[wid * 2 + 0] = w0;
        topi[wid * 2 + 1] = si;  topw[wid * 2 + 1] = w1;
        atomicAdd(&bc[bi], 1);
        atomicAdd(&bc[si], 1);
    }
    __syncthreads();
    if (threadIdx.x < NE) {
        int c = bc[threadIdx.x];
        if (c) atomicAdd(&counts[threadIdx.x], c);
    }
}

// -------- tiny scan: offsets + 128-slot tile prefix from counts -------------
__global__ __launch_bounds__(64) void k_scan(const int* __restrict__ counts,
                                             int* __restrict__ offsets,
                                             int* __restrict__ tileOff) {
    if (threadIdx.x == 0) {
        int acc = 0, tacc = 0;
        for (int j = 0; j < NE; ++j) {
            int cj = counts[j];
            offsets[j] = acc;   acc  += cj;
            tileOff[j] = tacc;  tacc += (cj + 127) >> 7;
        }
        tileOff[NE] = tacc;
    }
}

// ---------------- bucket fill: per-block aggregated atomics (8/block) -------
__global__ __launch_bounds__(256) void k_fill2(const int* __restrict__ topi,
                                               const float* __restrict__ topw,
                                               const int* __restrict__ offsets,
                                               int* __restrict__ fill,
                                               int* __restrict__ btok,
                                               float* __restrict__ bw,
                                               int* __restrict__ slotOf) {
    int tid = threadIdx.x;
    int i = blockIdx.x * 256 + tid;
    int w = tid >> 6, lane = tid & 63;
    int e = topi[i];
    float wt = topw[i];

    __shared__ int waveCnt[4][NE];
    __shared__ int wavePre[4][NE];
    __shared__ int baseSh[NE];

    int myrank = 0;
    unsigned long long lt = (1ull << lane) - 1ull;
#pragma unroll
    for (int j = 0; j < NE; ++j) {
        unsigned long long m = __ballot(e == j);
        if (e == j) myrank = __popcll(m & lt);
        if (lane == 0) waveCnt[w][j] = __popcll(m);
    }
    __syncthreads();
    if (tid < NE) {
        int j = tid, acc = 0;
#pragma unroll
        for (int ww = 0; ww < 4; ++ww) { wavePre[ww][j] = acc; acc += waveCnt[ww][j]; }
        baseSh[j] = atomicAdd(&fill[j], acc);
    }
    __syncthreads();
    int slot = offsets[e] + baseSh[e] + wavePre[w][e] + myrank;
    btok[slot] = i >> 1;
    bw[slot]   = wt;
    slotOf[i]  = slot;
}

// -------- fused weight transpose+convert: 3 tensors, one launch -------------
__global__ __launch_bounds__(256) void k_cvt3(const float* __restrict__ Wu,
                                              const float* __restrict__ Wv,
                                              const float* __restrict__ Wo,
                                              unsigned short* __restrict__ Wub,
                                              unsigned short* __restrict__ Wvb,
                                              unsigned short* __restrict__ Wob) {
    int z = blockIdx.y;
    int which = z >> 3, e = z & 7;
    int tile = blockIdx.x;
    const float* in; unsigned short* out;
    int M, N, n0, m0;
    if (which < 2) {
        M = DIM; N = RR;
        n0 = (tile & 7) * 32;  m0 = (tile >> 3) * 32;
        in = which ? Wv : Wu;  out = which ? Wvb : Wub;
    } else {
        M = RR; N = DIM;
        n0 = (tile & 31) * 32; m0 = (tile >> 5) * 32;
        in = Wo; out = Wob;
    }
    __shared__ float t[32][33];
    int tx = threadIdx.x & 31, ty = threadIdx.x >> 5;
    const float* inE = in + (size_t)e * M * N;
    unsigned short* outE = out + (size_t)e * M * N;
#pragma unroll
    for (int i = ty; i < 32; i += 8)
        t[i][tx] = inE[(size_t)(m0 + i) * N + n0 + tx];
    __syncthreads();
#pragma unroll
    for (int i = ty; i < 32; i += 8)
        outE[(size_t)(n0 + i) * M + m0 + tx] = f2bf(t[tx][i]);
}

// ---------------- UV kernel: S = silu(X Wu)*(X Wv)*gate ---------------------
// Round-3 proven config: single-buffered m97-style 128x128 tile, ~33 KB LDS,
// __launch_bounds__(256,2) (4 blocks/CU fit by LDS; cross-block TLP hides
// the per-kt vmcnt(0)+barrier drain). XOR-swizzled staging (rule #21).
// Grid 544 = 8*68, XCD-chunked: lt = (bid&7)*68 + bid>>3.
__global__ __launch_bounds__(256, 2) void k_uv(
        const unsigned short* __restrict__ xb,
        const unsigned short* __restrict__ Wub,   // [E][R][D] k-contig
        const unsigned short* __restrict__ Wvb,
        const int* __restrict__ counts,
        const int* __restrict__ offsets,
        const int* __restrict__ tileOff,
        const int* __restrict__ btok,
        const float* __restrict__ bw,
        unsigned short* __restrict__ Sbuf) {
    int bid = blockIdx.x;
    int lt  = (bid & 7) * 68 + (bid >> 3);   // bijective: 544 = 8*68
    int rt  = lt & 3;
    int mt_lin = lt >> 2;
    if (mt_lin >= tileOff[NE]) return;
    int e = 0;
#pragma unroll
    for (int j = 1; j < NE; ++j) if (mt_lin >= tileOff[j]) e = j;
    int t0 = (mt_lin - tileOff[e]) * 128;
    int ne = counts[e];
    int nt = min(128, ne - t0);
    int start = offsets[e] + t0;

    int tid = threadIdx.x;
    int w = tid >> 6, lane = tid & 63;
    int m16 = lane & 15, quad = lane >> 4;
    int wm = w & 1, wn = w >> 1;

    __shared__ unsigned short As[128][64];
    __shared__ unsigned short Bs[128][64];
    __shared__ int   tokL[128];
    __shared__ float gwL[128];

    if (tid < 128) {
        tokL[tid] = (tid < nt) ? btok[start + tid] : btok[start];
        gwL[tid]  = (tid < nt) ? bw[start + tid] : 0.f;
    }
    __syncthreads();

    int rc0 = rt * 64;
    const unsigned short* WuE = Wub + (size_t)e * RR * DIM;
    const unsigned short* WvE = Wvb + (size_t)e * RR * DIM;

    // staging descriptors: chunk c = w*4+i covers LDS rows [c*8, c*8+8);
    // lane covers row c*8 + lane/8, 16B unit j = lane&7, stored linearly;
    // global source pre-swizzled: unit js = j ^ (row&7)  (rule #21)
    const unsigned short* aS[4];
    const unsigned short* bS[4];
    int dstOff[4];
#pragma unroll
    for (int i = 0; i < 4; ++i) {
        int chunk = w * 4 + i;
        int row = chunk * 8 + (lane >> 3);
        int js  = (lane & 7) ^ (row & 7);
        aS[i] = xb + (size_t)tokL[row] * DIM + js * 8;
        bS[i] = ((row < 64) ? (WuE + (size_t)(rc0 + row) * DIM)
                            : (WvE + (size_t)(rc0 + row - 64) * DIM)) + js * 8;
        dstOff[i] = chunk * 1024;
    }
    auto* asb = (__attribute__((address_space(3))) char*)&As[0][0];
    auto* bsb = (__attribute__((address_space(3))) char*)&Bs[0][0];
    const char* Ab = (const char*)&As[0][0];
    const char* Bb = (const char*)&Bs[0][0];

    f32x4 accU[4][2], accV[4][2];
    f32x4 zz = {0.f, 0.f, 0.f, 0.f};
#pragma unroll
    for (int mt = 0; mt < 4; ++mt)
#pragma unroll
        for (int nl = 0; nl < 2; ++nl) { accU[mt][nl] = zz; accV[mt][nl] = zz; }

    for (int kt = 0; kt < 16; ++kt) {
        if (kt) __syncthreads();
#pragma unroll
        for (int i = 0; i < 4; ++i) {
            GLD16(aS[i] + kt * 64, asb + dstOff[i]);
            GLD16(bS[i] + kt * 64, bsb + dstOff[i]);
        }
        __syncthreads();
#pragma unroll
        for (int ks = 0; ks < 2; ++ks) {
            bf16x8 a[4], bu[2], bv[2];
#pragma unroll
            for (int mt = 0; mt < 4; ++mt) {
                int r = wm * 64 + mt * 16 + m16;
                int u = (ks * 4 + quad) ^ (r & 7);
                a[mt] = *(const bf16x8*)(Ab + r * 128 + u * 16);
            }
#pragma unroll
            for (int nl = 0; nl < 2; ++nl) {
                int r = wn * 32 + nl * 16 + m16;
                int u = (ks * 4 + quad) ^ (r & 7);
                bu[nl] = *(const bf16x8*)(Bb + r * 128 + u * 16);
                bv[nl] = *(const bf16x8*)(Bb + (r + 64) * 128 + u * 16);
            }
#pragma unroll
            for (int nl = 0; nl < 2; ++nl)
#pragma unroll
                for (int mt = 0; mt < 4; ++mt) {
                    accU[mt][nl] = __builtin_amdgcn_mfma_f32_16x16x32_bf16(a[mt], bu[nl], accU[mt][nl], 0, 0, 0);
                    accV[mt][nl] = __builtin_amdgcn_mfma_f32_16x16x32_bf16(a[mt], bv[nl], accV[mt][nl], 0, 0, 0);
                }
        }
    }

#pragma unroll
    for (int mt = 0; mt < 4; ++mt)
#pragma unroll
        for (int nl = 0; nl < 2; ++nl)
#pragma unroll
            for (int reg = 0; reg < 4; ++reg) {
                int trow = wm * 64 + mt * 16 + quad * 4 + reg;
                int rcol = rc0 + wn * 32 + nl * 16 + m16;
                float u = accU[mt][nl][reg], v = accV[mt][nl][reg];
                float s = (u / (1.f + __expf(-u))) * v * gwL[trow];
                if (trow < nt)
                    Sbuf[(size_t)(start + trow) * RR + rcol] = f2bf(s);
            }
}

// ---------------- down-proj: ybuf[slot] = S * WoT (no atomics) --------------
// Round-3 proven config. Grid 1088 = 8*136: lt = (bid&7)*136 + bid>>3;
// nd = lt&7, mt_lin = lt>>3.
__global__ __launch_bounds__(256, 2) void k_down(
        const unsigned short* __restrict__ Sbuf,
        const unsigned short* __restrict__ Wob,   // [E][D][R] k-contig
        const int* __restrict__ counts,
        const int* __restrict__ offsets,
        const int* __restrict__ tileOff,
        const int* __restrict__ btok,
        float* __restrict__ ybuf,                 // [slots][D] fp32, or null
        float* __restrict__ out) {
    int bid = blockIdx.x;
    int lt  = (bid & 7) * 136 + (bid >> 3);  // bijective: 1088 = 8*136
    int nd = lt & 7;
    int mt_lin = lt >> 3;
    if (mt_lin >= tileOff[NE]) return;
    int e = 0;
#pragma unroll
    for (int j = 1; j < NE; ++j) if (mt_lin >= tileOff[j]) e = j;
    int t0 = (mt_lin - tileOff[e]) * 128;
    int ne = counts[e];
    int nt = min(128, ne - t0);
    int start = offsets[e] + t0;

    int tid = threadIdx.x;
    int w = tid >> 6, lane = tid & 63;
    int m16 = lane & 15, quad = lane >> 4;
    int wm = w & 1, wn = w >> 1;

    __shared__ unsigned short As[128][64];
    __shared__ unsigned short Bs[128][64];
    __shared__ int tokL[128];

    if (tid < 128)
        tokL[tid] = (tid < nt) ? btok[start + tid] : btok[start];
    __syncthreads();

    const unsigned short* WoE = Wob + (size_t)e * DIM * RR;

    const unsigned short* aS[4];
    const unsigned short* bS[4];
    int dstOff[4];
#pragma unroll
    for (int i = 0; i < 4; ++i) {
        int chunk = w * 4 + i;
        int row = chunk * 8 + (lane >> 3);
        int js  = (lane & 7) ^ (row & 7);
        aS[i] = Sbuf + (size_t)(start + row) * RR + js * 8;
        bS[i] = WoE + (size_t)(nd * 128 + row) * RR + js * 8;
        dstOff[i] = chunk * 1024;
    }
    auto* asb = (__attribute__((address_space(3))) char*)&As[0][0];
    auto* bsb = (__attribute__((address_space(3))) char*)&Bs[0][0];
    const char* Ab = (const char*)&As[0][0];
    const char* Bb = (const char*)&Bs[0][0];

    f32x4 acc[4][4];
    f32x4 zz = {0.f, 0.f, 0.f, 0.f};
#pragma unroll
    for (int mt = 0; mt < 4; ++mt)
#pragma unroll
        for (int nl = 0; nl < 4; ++nl) acc[mt][nl] = zz;

    for (int kt = 0; kt < 4; ++kt) {
        if (kt) __syncthreads();
#pragma unroll
        for (int i = 0; i < 4; ++i) {
            GLD16(aS[i] + kt * 64, asb + dstOff[i]);
            GLD16(bS[i] + kt * 64, bsb + dstOff[i]);
        }
        __syncthreads();
#pragma unroll
        for (int ks = 0; ks < 2; ++ks) {
            bf16x8 a[4], b[4];
#pragma unroll
            for (int mt = 0; mt < 4; ++mt) {
                int r = wm * 64 + mt * 16 + m16;
                int u = (ks * 4 + quad) ^ (r & 7);
                a[mt] = *(const bf16x8*)(Ab + r * 128 + u * 16);
            }
#pragma unroll
            for (int nl = 0; nl < 4; ++nl) {
                int r = wn * 64 + nl * 16 + m16;
                int u = (ks * 4 + quad) ^ (r & 7);
                b[nl] = *(const bf16x8*)(Bb + r * 128 + u * 16);
            }
#pragma unroll
            for (int nl = 0; nl < 4; ++nl)
#pragma unroll
                for (int mt = 0; mt < 4; ++mt)
                    acc[mt][nl] = __builtin_amdgcn_mfma_f32_16x16x32_bf16(a[mt], b[nl], acc[mt][nl], 0, 0, 0);
        }
    }

    if (ybuf) {
#pragma unroll
        for (int mt = 0; mt < 4; ++mt)
#pragma unroll
            for (int nl = 0; nl < 4; ++nl)
#pragma unroll
                for (int reg = 0; reg < 4; ++reg) {
                    int srow = wm * 64 + mt * 16 + quad * 4 + reg;
                    int d    = nd * 128 + wn * 64 + nl * 16 + m16;
                    if (srow < nt)
                        ybuf[(size_t)(start + srow) * DIM + d] = acc[mt][nl][reg];
                }
    } else {
#pragma unroll
        for (int mt = 0; mt < 4; ++mt)
#pragma unroll
            for (int nl = 0; nl < 4; ++nl)
#pragma unroll
                for (int reg = 0; reg < 4; ++reg) {
                    int srow = wm * 64 + mt * 16 + quad * 4 + reg;
                    int d    = nd * 128 + wn * 64 + nl * 16 + m16;
                    if (srow < nt)
                        atomicAdd(&out[(size_t)tokL[srow] * DIM + d], acc[mt][nl][reg]);
                }
    }
}

// ---------------- combine: out[t] = ybuf[slot0] + ybuf[slot1] ----------------
__global__ __launch_bounds__(256) void k_combine(const float* __restrict__ ybuf,
                                                 const int* __restrict__ slotOf,
                                                 float* __restrict__ out) {
    int t   = blockIdx.x;
    int seg = threadIdx.x;
    int s0 = slotOf[t * 2 + 0];
    int s1 = slotOf[t * 2 + 1];
    float4 a = *(const float4*)(ybuf + (size_t)s0 * DIM + seg * 4);
    float4 b = *(const float4*)(ybuf + (size_t)s1 * DIM + seg * 4);
    float4 r = { a.x + b.x, a.y + b.y, a.z + b.z, a.w + b.w };
    *(float4*)(out + (size_t)t * DIM + seg * 4) = r;
}

extern "C" void kernel_launch(void* const* d_in, const int* in_sizes, int n_in,
                              void* d_out, int out_size, void* d_ws, size_t ws_size,
                              hipStream_t stream) {
    const float* x  = (const float*)d_in[0];
    const float* gw = (const float*)d_in[1];
    const float* Wu = (const float*)d_in[2];
    const float* Wv = (const float*)d_in[3];
    const float* Wo = (const float*)d_in[4];
    float* out = (float*)d_out;

    int*   wsi     = (int*)d_ws;
    int*   counts  = wsi + 0;
    int*   offsets = wsi + 8;
    int*   fill    = wsi + 16;
    int*   tileOff = wsi + 24;              // 9 ints
    int*   topi    = wsi + 48;
    float* topw    = (float*)(wsi + 48 + 16384);
    int*   btok    = wsi + 48 + 32768;
    float* bw      = (float*)(wsi + 48 + 49152);
    int*   slotOf  = wsi + 48 + 65536;
    // routing region ends at byte 4*(48+81920) = 327,872

    const size_t off_xb  = 393216;                                // 384 KB
    const size_t off_wub = off_xb  + (size_t)BN * DIM * 2;        // +16.78 MB
    const size_t off_wvb = off_wub + (size_t)NE * RR * DIM * 2;   // +4 MB
    const size_t off_wob = off_wvb + (size_t)NE * RR * DIM * 2;   // +4 MB
    const size_t off_sb  = off_wob + (size_t)NE * DIM * RR * 2;   // +4 MB
    const size_t off_yb  = off_sb  + (size_t)(BN * 2 + 128) * RR * 2; // +8.45 MB
    const size_t need_yb = off_yb  + (size_t)BN * 2 * DIM * 4;    // +67 MB ≈ 105 MB

    unsigned short* xb   = (unsigned short*)((char*)d_ws + off_xb);
    unsigned short* Wub  = (unsigned short*)((char*)d_ws + off_wub);
    unsigned short* Wvb  = (unsigned short*)((char*)d_ws + off_wvb);
    unsigned short* Wob  = (unsigned short*)((char*)d_ws + off_wob);
    unsigned short* Sbuf = (unsigned short*)((char*)d_ws + off_sb);
    bool use_ybuf = (ws_size >= need_yb);
    float* ybuf = use_ybuf ? (float*)((char*)d_ws + off_yb) : nullptr;

    // zero counts/offsets/fill/tileOff (33 ints)
    hipMemsetAsync(wsi, 0, 192, stream);

    k_router3<<<dim3(BN / 4), 256, 0, stream>>>(x, gw, topi, topw, xb, counts);
    k_scan<<<1, 64, 0, stream>>>(counts, offsets, tileOff);
    k_fill2<<<dim3(BN * 2 / 256), 256, 0, stream>>>(topi, topw, offsets, fill,
                                                    btok, bw, slotOf);
    k_cvt3<<<dim3(256, 24), 256, 0, stream>>>(Wu, Wv, Wo, Wub, Wvb, Wob);

    if (!use_ybuf)
        hipMemsetAsync(d_out, 0, (size_t)BN * DIM * sizeof(float), stream);

    k_uv<<<dim3(544), 256, 0, stream>>>(xb, Wub, Wvb, counts, offsets, tileOff,
                                        btok, bw, Sbuf);
    k_down<<<dim3(1088), 256, 0, stream>>>(Sbuf, Wob, counts, offsets, tileOff,
                                           btok, ybuf, out);
    if (use_ybuf)
        k_combine<<<dim3(BN), 256, 0, stream>>>(ybuf, slotOf, out);
}

// Round 7
// 201.315 us; speedup vs baseline: 1.0261x; 1.0261x over previous
//
#include <hip/hip_runtime.h>
#include <math.h>

#define BN 8192      // B*N tokens
#define DIM 1024     // D
#define NE 8         // E experts
#define RR 256       // R

using bf16x8 = __attribute__((ext_vector_type(8))) short;
using f32x4  = __attribute__((ext_vector_type(4))) float;

#define GLD16(g, l) __builtin_amdgcn_global_load_lds(                      \
    (const __attribute__((address_space(1))) void*)(g),                    \
    (__attribute__((address_space(3))) void*)(l), 16, 0, 0)

__device__ inline unsigned short f2bf(float f) {
    unsigned int u = __float_as_uint(f);
    u = (u + 0x7fffu + ((u >> 16) & 1u)) >> 16;
    return (unsigned short)u;
}

// ------- routing (gw native [D][E]) + x->bf16 + per-block counting ----------
// ILP-first layout: all x loads issued up front into named registers, gw
// loads issued in unrolled bursts, f2bf+stores last (nothing depends on
// them). Keeps ~36 loads in flight per wave -> BW-bound, not latency-bound.
__global__ __launch_bounds__(256) void k_router3(const float* __restrict__ x,
                                                 const float* __restrict__ gw,
                                                 int* __restrict__ topi,
                                                 float* __restrict__ topw,
                                                 unsigned short* __restrict__ xb,
                                                 int* __restrict__ counts) {
    int wid  = (blockIdx.x * blockDim.x + threadIdx.x) >> 6;
    int lane = threadIdx.x & 63;
    const float* xp = x + (size_t)wid * DIM + lane * 4;
    unsigned short* xbp = xb + (size_t)wid * DIM + lane * 4;

    // all x loads in flight first
    float4 xva[4];
#pragma unroll
    for (int k = 0; k < 4; ++k) xva[k] = *(const float4*)(xp + k * 256);

    // gate partials; gw loads burst-issued per k
    float lg[NE];
#pragma unroll
    for (int e = 0; e < NE; ++e) lg[e] = 0.f;
#pragma unroll
    for (int k = 0; k < 4; ++k) {
        const float* gp = gw + (size_t)(k * 256 + lane * 4) * NE;
        float4 g[8];
#pragma unroll
        for (int j = 0; j < 4; ++j) {
            g[2 * j]     = *(const float4*)(gp + j * NE);
            g[2 * j + 1] = *(const float4*)(gp + j * NE + 4);
        }
        float4 xv = xva[k];
#pragma unroll
        for (int j = 0; j < 4; ++j) {
            float xj = (j == 0) ? xv.x : (j == 1) ? xv.y : (j == 2) ? xv.z : xv.w;
            lg[0] += xj * g[2 * j].x; lg[1] += xj * g[2 * j].y;
            lg[2] += xj * g[2 * j].z; lg[3] += xj * g[2 * j].w;
            lg[4] += xj * g[2 * j + 1].x; lg[5] += xj * g[2 * j + 1].y;
            lg[6] += xj * g[2 * j + 1].z; lg[7] += xj * g[2 * j + 1].w;
        }
    }

    // bf16 conversion + stores last (no consumer)
#pragma unroll
    for (int k = 0; k < 4; ++k) {
        float4 xv = xva[k];
        ushort4 us = { f2bf(xv.x), f2bf(xv.y), f2bf(xv.z), f2bf(xv.w) };
        *(ushort4*)(xbp + k * 256) = us;
    }

#pragma unroll
    for (int off = 32; off; off >>= 1) {
#pragma unroll
        for (int e = 0; e < NE; ++e) lg[e] += __shfl_xor(lg[e], off, 64);
    }
    __shared__ int bc[NE];
    if (threadIdx.x < NE) bc[threadIdx.x] = 0;
    __syncthreads();
    if (lane == 0) {
        float best = lg[0]; int bi = 0;
#pragma unroll
        for (int e = 1; e < NE; ++e) if (lg[e] > best) { best = lg[e]; bi = e; }
        float sec = -3.4e38f; int si = 0;
#pragma unroll
        for (int e = 0; e < NE; ++e) if (e != bi && lg[e] > sec) { sec = lg[e]; si = e; }
        float p  = __expf(sec - best);
        float w0 = 1.f / (1.f + p);
        float w1 = p * w0;
        topi[wid * 2 + 0] = bi;  topw[wid * 2 + 0] = w0;
        topi[wid * 2 + 1] = si;  topw[wid * 2 + 1] = w1;
        atomicAdd(&bc[bi], 1);
        atomicAdd(&bc[si], 1);
    }
    __syncthreads();
    if (threadIdx.x < NE) {
        int c = bc[threadIdx.x];
        if (c) atomicAdd(&counts[threadIdx.x], c);
    }
}

// ---------------- bucket fill: offsets computed in-block from counts --------
__global__ __launch_bounds__(256) void k_fill2(const int* __restrict__ topi,
                                               const float* __restrict__ topw,
                                               const int* __restrict__ counts,
                                               int* __restrict__ fill,
                                               int* __restrict__ btok,
                                               float* __restrict__ bw,
                                               int* __restrict__ slotOf) {
    int tid = threadIdx.x;
    int i = blockIdx.x * 256 + tid;
    int w = tid >> 6, lane = tid & 63;
    int e = topi[i];
    float wt = topw[i];

    __shared__ int waveCnt[4][NE];
    __shared__ int wavePre[4][NE];
    __shared__ int baseSh[NE];
    __shared__ int offSh[NE];

    int myrank = 0;
    unsigned long long lt = (1ull << lane) - 1ull;
#pragma unroll
    for (int j = 0; j < NE; ++j) {
        unsigned long long m = __ballot(e == j);
        if (e == j) myrank = __popcll(m & lt);
        if (lane == 0) waveCnt[w][j] = __popcll(m);
    }
    if (tid == 0) {
        int acc = 0;
#pragma unroll
        for (int j = 0; j < NE; ++j) { offSh[j] = acc; acc += counts[j]; }
    }
    __syncthreads();
    if (tid < NE) {
        int j = tid, acc = 0;
#pragma unroll
        for (int ww = 0; ww < 4; ++ww) { wavePre[ww][j] = acc; acc += waveCnt[ww][j]; }
        baseSh[j] = atomicAdd(&fill[j], acc);
    }
    __syncthreads();
    int slot = offSh[e] + baseSh[e] + wavePre[w][e] + myrank;
    btok[slot] = i >> 1;
    bw[slot]   = wt;
    slotOf[i]  = slot;
}

// -------- fused weight transpose+convert: 3 tensors, one launch -------------
__global__ __launch_bounds__(256) void k_cvt3(const float* __restrict__ Wu,
                                              const float* __restrict__ Wv,
                                              const float* __restrict__ Wo,
                                              unsigned short* __restrict__ Wub,
                                              unsigned short* __restrict__ Wvb,
                                              unsigned short* __restrict__ Wob) {
    int z = blockIdx.y;
    int which = z >> 3, e = z & 7;
    int tile = blockIdx.x;
    const float* in; unsigned short* out;
    int M, N, n0, m0;
    if (which < 2) {
        M = DIM; N = RR;
        n0 = (tile & 7) * 32;  m0 = (tile >> 3) * 32;
        in = which ? Wv : Wu;  out = which ? Wvb : Wub;
    } else {
        M = RR; N = DIM;
        n0 = (tile & 31) * 32; m0 = (tile >> 5) * 32;
        in = Wo; out = Wob;
    }
    __shared__ float t[32][33];
    int tx = threadIdx.x & 31, ty = threadIdx.x >> 5;
    const float* inE = in + (size_t)e * M * N;
    unsigned short* outE = out + (size_t)e * M * N;
#pragma unroll
    for (int i = ty; i < 32; i += 8)
        t[i][tx] = inE[(size_t)(m0 + i) * N + n0 + tx];
    __syncthreads();
#pragma unroll
    for (int i = ty; i < 32; i += 8)
        outE[(size_t)(n0 + i) * M + m0 + tx] = f2bf(t[tx][i]);
}

// -------- inline tile decode from counts (replaces offsets/tileOff) ---------
__device__ inline bool decode_tile(const int* __restrict__ counts, int mt_lin,
                                   int& e, int& start, int& nt) {
    int acc = 0, tacc = 0;
    e = -1;
    int t0 = 0, ne = 0;
#pragma unroll
    for (int j = 0; j < NE; ++j) {
        int cj = counts[j];
        int tj = (cj + 127) >> 7;
        if (e < 0 && mt_lin < tacc + tj) {
            e = j; t0 = (mt_lin - tacc) * 128; start = acc + t0; ne = cj;
        }
        tacc += tj; acc += cj;
    }
    if (e < 0) return false;
    nt = min(128, ne - t0);
    return true;
}

// ---------------- UV kernel: S = silu(X Wu)*(X Wv)*gate ---------------------
// Round-3 proven config: single-buffered m97-style 128x128 tile, ~33 KB LDS,
// __launch_bounds__(256,2) (4 blocks/CU fit by LDS; cross-block TLP hides
// the per-kt vmcnt(0)+barrier drain). XOR-swizzled staging (rule #21).
// Grid 544 = 8*68, XCD-chunked: lt = (bid&7)*68 + bid>>3.
__global__ __launch_bounds__(256, 2) void k_uv(
        const unsigned short* __restrict__ xb,
        const unsigned short* __restrict__ Wub,   // [E][R][D] k-contig
        const unsigned short* __restrict__ Wvb,
        const int* __restrict__ counts,
        const int* __restrict__ btok,
        const float* __restrict__ bw,
        unsigned short* __restrict__ Sbuf) {
    int bid = blockIdx.x;
    int lt  = (bid & 7) * 68 + (bid >> 3);   // bijective: 544 = 8*68
    int rt  = lt & 3;
    int mt_lin = lt >> 2;
    int e, start, nt;
    if (!decode_tile(counts, mt_lin, e, start, nt)) return;

    int tid = threadIdx.x;
    int w = tid >> 6, lane = tid & 63;
    int m16 = lane & 15, quad = lane >> 4;
    int wm = w & 1, wn = w >> 1;

    __shared__ unsigned short As[128][64];
    __shared__ unsigned short Bs[128][64];
    __shared__ int   tokL[128];
    __shared__ float gwL[128];

    if (tid < 128) {
        tokL[tid] = (tid < nt) ? btok[start + tid] : btok[start];
        gwL[tid]  = (tid < nt) ? bw[start + tid] : 0.f;
    }
    __syncthreads();

    int rc0 = rt * 64;
    const unsigned short* WuE = Wub + (size_t)e * RR * DIM;
    const unsigned short* WvE = Wvb + (size_t)e * RR * DIM;

    // staging descriptors: chunk c = w*4+i covers LDS rows [c*8, c*8+8);
    // lane covers row c*8 + lane/8, 16B unit j = lane&7, stored linearly;
    // global source pre-swizzled: unit js = j ^ (row&7)  (rule #21)
    const unsigned short* aS[4];
    const unsigned short* bS[4];
    int dstOff[4];
#pragma unroll
    for (int i = 0; i < 4; ++i) {
        int chunk = w * 4 + i;
        int row = chunk * 8 + (lane >> 3);
        int js  = (lane & 7) ^ (row & 7);
        aS[i] = xb + (size_t)tokL[row] * DIM + js * 8;
        bS[i] = ((row < 64) ? (WuE + (size_t)(rc0 + row) * DIM)
                            : (WvE + (size_t)(rc0 + row - 64) * DIM)) + js * 8;
        dstOff[i] = chunk * 1024;
    }
    auto* asb = (__attribute__((address_space(3))) char*)&As[0][0];
    auto* bsb = (__attribute__((address_space(3))) char*)&Bs[0][0];
    const char* Ab = (const char*)&As[0][0];
    const char* Bb = (const char*)&Bs[0][0];

    f32x4 accU[4][2], accV[4][2];
    f32x4 zz = {0.f, 0.f, 0.f, 0.f};
#pragma unroll
    for (int mt = 0; mt < 4; ++mt)
#pragma unroll
        for (int nl = 0; nl < 2; ++nl) { accU[mt][nl] = zz; accV[mt][nl] = zz; }

    for (int kt = 0; kt < 16; ++kt) {
        if (kt) __syncthreads();
#pragma unroll
        for (int i = 0; i < 4; ++i) {
            GLD16(aS[i] + kt * 64, asb + dstOff[i]);
            GLD16(bS[i] + kt * 64, bsb + dstOff[i]);
        }
        __syncthreads();
#pragma unroll
        for (int ks = 0; ks < 2; ++ks) {
            bf16x8 a[4], bu[2], bv[2];
#pragma unroll
            for (int mt = 0; mt < 4; ++mt) {
                int r = wm * 64 + mt * 16 + m16;
                int u = (ks * 4 + quad) ^ (r & 7);
                a[mt] = *(const bf16x8*)(Ab + r * 128 + u * 16);
            }
#pragma unroll
            for (int nl = 0; nl < 2; ++nl) {
                int r = wn * 32 + nl * 16 + m16;
                int u = (ks * 4 + quad) ^ (r & 7);
                bu[nl] = *(const bf16x8*)(Bb + r * 128 + u * 16);
                bv[nl] = *(const bf16x8*)(Bb + (r + 64) * 128 + u * 16);
            }
#pragma unroll
            for (int nl = 0; nl < 2; ++nl)
#pragma unroll
                for (int mt = 0; mt < 4; ++mt) {
                    accU[mt][nl] = __builtin_amdgcn_mfma_f32_16x16x32_bf16(a[mt], bu[nl], accU[mt][nl], 0, 0, 0);
                    accV[mt][nl] = __builtin_amdgcn_mfma_f32_16x16x32_bf16(a[mt], bv[nl], accV[mt][nl], 0, 0, 0);
                }
        }
    }

#pragma unroll
    for (int mt = 0; mt < 4; ++mt)
#pragma unroll
        for (int nl = 0; nl < 2; ++nl)
#pragma unroll
            for (int reg = 0; reg < 4; ++reg) {
                int trow = wm * 64 + mt * 16 + quad * 4 + reg;
                int rcol = rc0 + wn * 32 + nl * 16 + m16;
                float u = accU[mt][nl][reg], v = accV[mt][nl][reg];
                float s = (u / (1.f + __expf(-u))) * v * gwL[trow];
                if (trow < nt)
                    Sbuf[(size_t)(start + trow) * RR + rcol] = f2bf(s);
            }
}

// ---------------- down-proj: ybuf[slot] = S * WoT (no atomics) --------------
// Round-3 proven config. Grid 1088 = 8*136: lt = (bid&7)*136 + bid>>3;
// nd = lt&7, mt_lin = lt>>3.
__global__ __launch_bounds__(256, 2) void k_down(
        const unsigned short* __restrict__ Sbuf,
        const unsigned short* __restrict__ Wob,   // [E][D][R] k-contig
        const int* __restrict__ counts,
        const int* __restrict__ btok,
        float* __restrict__ ybuf,                 // [slots][D] fp32, or null
        float* __restrict__ out) {
    int bid = blockIdx.x;
    int lt  = (bid & 7) * 136 + (bid >> 3);  // bijective: 1088 = 8*136
    int nd = lt & 7;
    int mt_lin = lt >> 3;
    int e, start, nt;
    if (!decode_tile(counts, mt_lin, e, start, nt)) return;

    int tid = threadIdx.x;
    int w = tid >> 6, lane = tid & 63;
    int m16 = lane & 15, quad = lane >> 4;
    int wm = w & 1, wn = w >> 1;

    __shared__ unsigned short As[128][64];
    __shared__ unsigned short Bs[128][64];
    __shared__ int tokL[128];

    if (tid < 128)
        tokL[tid] = (tid < nt) ? btok[start + tid] : btok[start];
    __syncthreads();

    const unsigned short* WoE = Wob + (size_t)e * DIM * RR;

    const unsigned short* aS[4];
    const unsigned short* bS[4];
    int dstOff[4];
#pragma unroll
    for (int i = 0; i < 4; ++i) {
        int chunk = w * 4 + i;
        int row = chunk * 8 + (lane >> 3);
        int js  = (lane & 7) ^ (row & 7);
        aS[i] = Sbuf + (size_t)(start + row) * RR + js * 8;
        bS[i] = WoE + (size_t)(nd * 128 + row) * RR + js * 8;
        dstOff[i] = chunk * 1024;
    }
    auto* asb = (__attribute__((address_space(3))) char*)&As[0][0];
    auto* bsb = (__attribute__((address_space(3))) char*)&Bs[0][0];
    const char* Ab = (const char*)&As[0][0];
    const char* Bb = (const char*)&Bs[0][0];

    f32x4 acc[4][4];
    f32x4 zz = {0.f, 0.f, 0.f, 0.f};
#pragma unroll
    for (int mt = 0; mt < 4; ++mt)
#pragma unroll
        for (int nl = 0; nl < 4; ++nl) acc[mt][nl] = zz;

    for (int kt = 0; kt < 4; ++kt) {
        if (kt) __syncthreads();
#pragma unroll
        for (int i = 0; i < 4; ++i) {
            GLD16(aS[i] + kt * 64, asb + dstOff[i]);
            GLD16(bS[i] + kt * 64, bsb + dstOff[i]);
        }
        __syncthreads();
#pragma unroll
        for (int ks = 0; ks < 2; ++ks) {
            bf16x8 a[4], b[4];
#pragma unroll
            for (int mt = 0; mt < 4; ++mt) {
                int r = wm * 64 + mt * 16 + m16;
                int u = (ks * 4 + quad) ^ (r & 7);
                a[mt] = *(const bf16x8*)(Ab + r * 128 + u * 16);
            }
#pragma unroll
            for (int nl = 0; nl < 4; ++nl) {
                int r = wn * 64 + nl * 16 + m16;
                int u = (ks * 4 + quad) ^ (r & 7);
                b[nl] = *(const bf16x8*)(Bb + r * 128 + u * 16);
            }
#pragma unroll
            for (int nl = 0; nl < 4; ++nl)
#pragma unroll
                for (int mt = 0; mt < 4; ++mt)
                    acc[mt][nl] = __builtin_amdgcn_mfma_f32_16x16x32_bf16(a[mt], b[nl], acc[mt][nl], 0, 0, 0);
        }
    }

    if (ybuf) {
#pragma unroll
        for (int mt = 0; mt < 4; ++mt)
#pragma unroll
            for (int nl = 0; nl < 4; ++nl)
#pragma unroll
                for (int reg = 0; reg < 4; ++reg) {
                    int srow = wm * 64 + mt * 16 + quad * 4 + reg;
                    int d    = nd * 128 + wn * 64 + nl * 16 + m16;
                    if (srow < nt)
                        ybuf[(size_t)(start + srow) * DIM + d] = acc[mt][nl][reg];
                }
    } else {
#pragma unroll
        for (int mt = 0; mt < 4; ++mt)
#pragma unroll
            for (int nl = 0; nl < 4; ++nl)
#pragma unroll
                for (int reg = 0; reg < 4; ++reg) {
                    int srow = wm * 64 + mt * 16 + quad * 4 + reg;
                    int d    = nd * 128 + wn * 64 + nl * 16 + m16;
                    if (srow < nt)
                        atomicAdd(&out[(size_t)tokL[srow] * DIM + d], acc[mt][nl][reg]);
                }
    }
}

// ---------------- combine: out[t] = ybuf[slot0] + ybuf[slot1] ----------------
__global__ __launch_bounds__(256) void k_combine(const float* __restrict__ ybuf,
                                                 const int* __restrict__ slotOf,
                                                 float* __restrict__ out) {
    int t   = blockIdx.x;
    int seg = threadIdx.x;
    int s0 = slotOf[t * 2 + 0];
    int s1 = slotOf[t * 2 + 1];
    float4 a = *(const float4*)(ybuf + (size_t)s0 * DIM + seg * 4);
    float4 b = *(const float4*)(ybuf + (size_t)s1 * DIM + seg * 4);
    float4 r = { a.x + b.x, a.y + b.y, a.z + b.z, a.w + b.w };
    *(float4*)(out + (size_t)t * DIM + seg * 4) = r;
}

extern "C" void kernel_launch(void* const* d_in, const int* in_sizes, int n_in,
                              void* d_out, int out_size, void* d_ws, size_t ws_size,
                              hipStream_t stream) {
    const float* x  = (const float*)d_in[0];
    const float* gw = (const float*)d_in[1];
    const float* Wu = (const float*)d_in[2];
    const float* Wv = (const float*)d_in[3];
    const float* Wo = (const float*)d_in[4];
    float* out = (float*)d_out;

    int*   wsi     = (int*)d_ws;
    int*   counts  = wsi + 0;
    int*   fill    = wsi + 16;
    int*   topi    = wsi + 48;
    float* topw    = (float*)(wsi + 48 + 16384);
    int*   btok    = wsi + 48 + 32768;
    float* bw      = (float*)(wsi + 48 + 49152);
    int*   slotOf  = wsi + 48 + 65536;
    // routing region ends at byte 4*(48+81920) = 327,872

    const size_t off_xb  = 393216;                                // 384 KB
    const size_t off_wub = off_xb  + (size_t)BN * DIM * 2;        // +16.78 MB
    const size_t off_wvb = off_wub + (size_t)NE * RR * DIM * 2;   // +4 MB
    const size_t off_wob = off_wvb + (size_t)NE * RR * DIM * 2;   // +4 MB
    const size_t off_sb  = off_wob + (size_t)NE * DIM * RR * 2;   // +4 MB
    const size_t off_yb  = off_sb  + (size_t)(BN * 2 + 128) * RR * 2; // +8.45 MB
    const size_t need_yb = off_yb  + (size_t)BN * 2 * DIM * 4;    // +67 MB ≈ 105 MB

    unsigned short* xb   = (unsigned short*)((char*)d_ws + off_xb);
    unsigned short* Wub  = (unsigned short*)((char*)d_ws + off_wub);
    unsigned short* Wvb  = (unsigned short*)((char*)d_ws + off_wvb);
    unsigned short* Wob  = (unsigned short*)((char*)d_ws + off_wob);
    unsigned short* Sbuf = (unsigned short*)((char*)d_ws + off_sb);
    bool use_ybuf = (ws_size >= need_yb);
    float* ybuf = use_ybuf ? (float*)((char*)d_ws + off_yb) : nullptr;

    // zero counts/fill (48 ints incl. padding)
    hipMemsetAsync(wsi, 0, 192, stream);

    k_router3<<<dim3(BN / 4), 256, 0, stream>>>(x, gw, topi, topw, xb, counts);
    k_fill2<<<dim3(BN * 2 / 256), 256, 0, stream>>>(topi, topw, counts, fill,
                                                    btok, bw, slotOf);
    k_cvt3<<<dim3(256, 24), 256, 0, stream>>>(Wu, Wv, Wo, Wub, Wvb, Wob);

    if (!use_ybuf)
        hipMemsetAsync(d_out, 0, (size_t)BN * DIM * sizeof(float), stream);

    k_uv<<<dim3(544), 256, 0, stream>>>(xb, Wub, Wvb, counts, btok, bw, Sbuf);
    k_down<<<dim3(1088), 256, 0, stream>>>(Sbuf, Wob, counts, btok, ybuf, out);
    if (use_ybuf)
        k_combine<<<dim3(BN), 256, 0, stream>>>(ybuf, slotOf, out);
}

// Round 8
// 197.651 us; speedup vs baseline: 1.0451x; 1.0185x over previous
//
#include <hip/hip_runtime.h>
#include <math.h>

#define BN 8192      // B*N tokens
#define DIM 1024     // D
#define NE 8         // E experts
#define RR 256       // R

using bf16x8 = __attribute__((ext_vector_type(8))) short;
using f32x4  = __attribute__((ext_vector_type(4))) float;

#define GLD16(g, l) __builtin_amdgcn_global_load_lds(                      \
    (const __attribute__((address_space(1))) void*)(g),                    \
    (__attribute__((address_space(3))) void*)(l), 16, 0, 0)

__device__ inline unsigned short f2bf(float f) {
    unsigned int u = __float_as_uint(f);
    u = (u + 0x7fffu + ((u >> 16) & 1u)) >> 16;
    return (unsigned short)u;
}

// ---------------- gw transpose: [D][E] -> [E][D] fp32 ----------------
// Coalesced gwT reads in the router are worth far more than this launch:
// native-layout gw reads put lanes 128B apart (64-line replay per load).
__global__ __launch_bounds__(256) void k_gwt(const float* __restrict__ gw,
                                             float* __restrict__ gwT) {
    int i = blockIdx.x * 256 + threadIdx.x;
    float v = gw[i];
    int d = i >> 3, e = i & 7;
    gwT[e * DIM + d] = v;
}

// ------- routing (coalesced gwT) + x->bf16 + per-block counting -------------
__global__ __launch_bounds__(256) void k_router3(const float* __restrict__ x,
                                                 const float* __restrict__ gwT,
                                                 int* __restrict__ topi,
                                                 float* __restrict__ topw,
                                                 unsigned short* __restrict__ xb,
                                                 int* __restrict__ counts) {
    int wid  = (blockIdx.x * blockDim.x + threadIdx.x) >> 6;
    int lane = threadIdx.x & 63;
    const float* xp = x + (size_t)wid * DIM + lane * 4;
    unsigned short* xbp = xb + (size_t)wid * DIM + lane * 4;

    // all x loads in flight first
    float4 xva[4];
#pragma unroll
    for (int k = 0; k < 4; ++k) xva[k] = *(const float4*)(xp + k * 256);

    float4 acc[NE];
#pragma unroll
    for (int e = 0; e < NE; ++e) acc[e] = float4{0.f, 0.f, 0.f, 0.f};
#pragma unroll
    for (int k = 0; k < 4; ++k) {
        float4 xv = xva[k];
#pragma unroll
        for (int e = 0; e < NE; ++e) {
            float4 gv = *(const float4*)(gwT + e * DIM + k * 256 + lane * 4);
            acc[e].x += xv.x * gv.x; acc[e].y += xv.y * gv.y;
            acc[e].z += xv.z * gv.z; acc[e].w += xv.w * gv.w;
        }
    }

    // bf16 conversion + stores last (no consumer)
#pragma unroll
    for (int k = 0; k < 4; ++k) {
        float4 xv = xva[k];
        ushort4 us = { f2bf(xv.x), f2bf(xv.y), f2bf(xv.z), f2bf(xv.w) };
        *(ushort4*)(xbp + k * 256) = us;
    }

    float lg[NE];
#pragma unroll
    for (int e = 0; e < NE; ++e)
        lg[e] = (acc[e].x + acc[e].y) + (acc[e].z + acc[e].w);
#pragma unroll
    for (int off = 32; off; off >>= 1) {
#pragma unroll
        for (int e = 0; e < NE; ++e) lg[e] += __shfl_xor(lg[e], off, 64);
    }
    __shared__ int bc[NE];
    if (threadIdx.x < NE) bc[threadIdx.x] = 0;
    __syncthreads();
    if (lane == 0) {
        float best = lg[0]; int bi = 0;
#pragma unroll
        for (int e = 1; e < NE; ++e) if (lg[e] > best) { best = lg[e]; bi = e; }
        float sec = -3.4e38f; int si = 0;
#pragma unroll
        for (int e = 0; e < NE; ++e) if (e != bi && lg[e] > sec) { sec = lg[e]; si = e; }
        float p  = __expf(sec - best);
        float w0 = 1.f / (1.f + p);
        float w1 = p * w0;
        topi[wid * 2 + 0] = bi;  topw[wid * 2 + 0] = w0;
        topi[wid * 2 + 1] = si;  topw[wid * 2 + 1] = w1;
        atomicAdd(&bc[bi], 1);
        atomicAdd(&bc[si], 1);
    }
    __syncthreads();
    if (threadIdx.x < NE) {
        int c = bc[threadIdx.x];
        if (c) atomicAdd(&counts[threadIdx.x], c);
    }
}

// ---------------- bucket fill: offsets computed in-block from counts --------
__global__ __launch_bounds__(256) void k_fill2(const int* __restrict__ topi,
                                               const float* __restrict__ topw,
                                               const int* __restrict__ counts,
                                               int* __restrict__ fill,
                                               int* __restrict__ btok,
                                               float* __restrict__ bw,
                                               int* __restrict__ slotOf) {
    int tid = threadIdx.x;
    int i = blockIdx.x * 256 + tid;
    int w = tid >> 6, lane = tid & 63;
    int e = topi[i];
    float wt = topw[i];

    __shared__ int waveCnt[4][NE];
    __shared__ int wavePre[4][NE];
    __shared__ int baseSh[NE];
    __shared__ int offSh[NE];

    int myrank = 0;
    unsigned long long lt = (1ull << lane) - 1ull;
#pragma unroll
    for (int j = 0; j < NE; ++j) {
        unsigned long long m = __ballot(e == j);
        if (e == j) myrank = __popcll(m & lt);
        if (lane == 0) waveCnt[w][j] = __popcll(m);
    }
    if (tid == 0) {
        int acc = 0;
#pragma unroll
        for (int j = 0; j < NE; ++j) { offSh[j] = acc; acc += counts[j]; }
    }
    __syncthreads();
    if (tid < NE) {
        int j = tid, acc = 0;
#pragma unroll
        for (int ww = 0; ww < 4; ++ww) { wavePre[ww][j] = acc; acc += waveCnt[ww][j]; }
        baseSh[j] = atomicAdd(&fill[j], acc);
    }
    __syncthreads();
    int slot = offSh[e] + baseSh[e] + wavePre[w][e] + myrank;
    btok[slot] = i >> 1;
    bw[slot]   = wt;
    slotOf[i]  = slot;
}

// -------- fused weight transpose+convert: 3 tensors, one launch -------------
__global__ __launch_bounds__(256) void k_cvt3(const float* __restrict__ Wu,
                                              const float* __restrict__ Wv,
                                              const float* __restrict__ Wo,
                                              unsigned short* __restrict__ Wub,
                                              unsigned short* __restrict__ Wvb,
                                              unsigned short* __restrict__ Wob) {
    int z = blockIdx.y;
    int which = z >> 3, e = z & 7;
    int tile = blockIdx.x;
    const float* in; unsigned short* out;
    int M, N, n0, m0;
    if (which < 2) {
        M = DIM; N = RR;
        n0 = (tile & 7) * 32;  m0 = (tile >> 3) * 32;
        in = which ? Wv : Wu;  out = which ? Wvb : Wub;
    } else {
        M = RR; N = DIM;
        n0 = (tile & 31) * 32; m0 = (tile >> 5) * 32;
        in = Wo; out = Wob;
    }
    __shared__ float t[32][33];
    int tx = threadIdx.x & 31, ty = threadIdx.x >> 5;
    const float* inE = in + (size_t)e * M * N;
    unsigned short* outE = out + (size_t)e * M * N;
#pragma unroll
    for (int i = ty; i < 32; i += 8)
        t[i][tx] = inE[(size_t)(m0 + i) * N + n0 + tx];
    __syncthreads();
#pragma unroll
    for (int i = ty; i < 32; i += 8)
        outE[(size_t)(n0 + i) * M + m0 + tx] = f2bf(t[tx][i]);
}

// -------- inline tile decode from counts (replaces offsets/tileOff) ---------
__device__ inline bool decode_tile(const int* __restrict__ counts, int mt_lin,
                                   int& e, int& start, int& nt) {
    int acc = 0, tacc = 0;
    e = -1;
    int t0 = 0, ne = 0;
#pragma unroll
    for (int j = 0; j < NE; ++j) {
        int cj = counts[j];
        int tj = (cj + 127) >> 7;
        if (e < 0 && mt_lin < tacc + tj) {
            e = j; t0 = (mt_lin - tacc) * 128; start = acc + t0; ne = cj;
        }
        tacc += tj; acc += cj;
    }
    if (e < 0) return false;
    nt = min(128, ne - t0);
    return true;
}

// ---------------- UV kernel: S = silu(X Wu)*(X Wv)*gate ---------------------
// Round-3 proven config: single-buffered m97-style 128x128 tile, ~33 KB LDS,
// __launch_bounds__(256,2) (4 blocks/CU fit by LDS; cross-block TLP hides
// the per-kt vmcnt(0)+barrier drain). XOR-swizzled staging (rule #21).
// Grid 544 = 8*68, XCD-chunked: lt = (bid&7)*68 + bid>>3.
__global__ __launch_bounds__(256, 2) void k_uv(
        const unsigned short* __restrict__ xb,
        const unsigned short* __restrict__ Wub,   // [E][R][D] k-contig
        const unsigned short* __restrict__ Wvb,
        const int* __restrict__ counts,
        const int* __restrict__ btok,
        const float* __restrict__ bw,
        unsigned short* __restrict__ Sbuf) {
    int bid = blockIdx.x;
    int lt  = (bid & 7) * 68 + (bid >> 3);   // bijective: 544 = 8*68
    int rt  = lt & 3;
    int mt_lin = lt >> 2;
    int e, start, nt;
    if (!decode_tile(counts, mt_lin, e, start, nt)) return;

    int tid = threadIdx.x;
    int w = tid >> 6, lane = tid & 63;
    int m16 = lane & 15, quad = lane >> 4;
    int wm = w & 1, wn = w >> 1;

    __shared__ unsigned short As[128][64];
    __shared__ unsigned short Bs[128][64];
    __shared__ int   tokL[128];
    __shared__ float gwL[128];

    if (tid < 128) {
        tokL[tid] = (tid < nt) ? btok[start + tid] : btok[start];
        gwL[tid]  = (tid < nt) ? bw[start + tid] : 0.f;
    }
    __syncthreads();

    int rc0 = rt * 64;
    const unsigned short* WuE = Wub + (size_t)e * RR * DIM;
    const unsigned short* WvE = Wvb + (size_t)e * RR * DIM;

    // staging descriptors: chunk c = w*4+i covers LDS rows [c*8, c*8+8);
    // lane covers row c*8 + lane/8, 16B unit j = lane&7, stored linearly;
    // global source pre-swizzled: unit js = j ^ (row&7)  (rule #21)
    const unsigned short* aS[4];
    const unsigned short* bS[4];
    int dstOff[4];
#pragma unroll
    for (int i = 0; i < 4; ++i) {
        int chunk = w * 4 + i;
        int row = chunk * 8 + (lane >> 3);
        int js  = (lane & 7) ^ (row & 7);
        aS[i] = xb + (size_t)tokL[row] * DIM + js * 8;
        bS[i] = ((row < 64) ? (WuE + (size_t)(rc0 + row) * DIM)
                            : (WvE + (size_t)(rc0 + row - 64) * DIM)) + js * 8;
        dstOff[i] = chunk * 1024;
    }
    auto* asb = (__attribute__((address_space(3))) char*)&As[0][0];
    auto* bsb = (__attribute__((address_space(3))) char*)&Bs[0][0];
    const char* Ab = (const char*)&As[0][0];
    const char* Bb = (const char*)&Bs[0][0];

    f32x4 accU[4][2], accV[4][2];
    f32x4 zz = {0.f, 0.f, 0.f, 0.f};
#pragma unroll
    for (int mt = 0; mt < 4; ++mt)
#pragma unroll
        for (int nl = 0; nl < 2; ++nl) { accU[mt][nl] = zz; accV[mt][nl] = zz; }

    for (int kt = 0; kt < 16; ++kt) {
        if (kt) __syncthreads();
#pragma unroll
        for (int i = 0; i < 4; ++i) {
            GLD16(aS[i] + kt * 64, asb + dstOff[i]);
            GLD16(bS[i] + kt * 64, bsb + dstOff[i]);
        }
        __syncthreads();
#pragma unroll
        for (int ks = 0; ks < 2; ++ks) {
            bf16x8 a[4], bu[2], bv[2];
#pragma unroll
            for (int mt = 0; mt < 4; ++mt) {
                int r = wm * 64 + mt * 16 + m16;
                int u = (ks * 4 + quad) ^ (r & 7);
                a[mt] = *(const bf16x8*)(Ab + r * 128 + u * 16);
            }
#pragma unroll
            for (int nl = 0; nl < 2; ++nl) {
                int r = wn * 32 + nl * 16 + m16;
                int u = (ks * 4 + quad) ^ (r & 7);
                bu[nl] = *(const bf16x8*)(Bb + r * 128 + u * 16);
                bv[nl] = *(const bf16x8*)(Bb + (r + 64) * 128 + u * 16);
            }
#pragma unroll
            for (int nl = 0; nl < 2; ++nl)
#pragma unroll
                for (int mt = 0; mt < 4; ++mt) {
                    accU[mt][nl] = __builtin_amdgcn_mfma_f32_16x16x32_bf16(a[mt], bu[nl], accU[mt][nl], 0, 0, 0);
                    accV[mt][nl] = __builtin_amdgcn_mfma_f32_16x16x32_bf16(a[mt], bv[nl], accV[mt][nl], 0, 0, 0);
                }
        }
    }

#pragma unroll
    for (int mt = 0; mt < 4; ++mt)
#pragma unroll
        for (int nl = 0; nl < 2; ++nl)
#pragma unroll
            for (int reg = 0; reg < 4; ++reg) {
                int trow = wm * 64 + mt * 16 + quad * 4 + reg;
                int rcol = rc0 + wn * 32 + nl * 16 + m16;
                float u = accU[mt][nl][reg], v = accV[mt][nl][reg];
                float s = (u / (1.f + __expf(-u))) * v * gwL[trow];
                if (trow < nt)
                    Sbuf[(size_t)(start + trow) * RR + rcol] = f2bf(s);
            }
}

// ---------------- down-proj: ybuf[slot] = S * WoT (no atomics) --------------
// Round-3 proven config. Grid 1088 = 8*136: lt = (bid&7)*136 + bid>>3;
// nd = lt&7, mt_lin = lt>>3.
__global__ __launch_bounds__(256, 2) void k_down(
        const unsigned short* __restrict__ Sbuf,
        const unsigned short* __restrict__ Wob,   // [E][D][R] k-contig
        const int* __restrict__ counts,
        const int* __restrict__ btok,
        float* __restrict__ ybuf,                 // [slots][D] fp32, or null
        float* __restrict__ out) {
    int bid = blockIdx.x;
    int lt  = (bid & 7) * 136 + (bid >> 3);  // bijective: 1088 = 8*136
    int nd = lt & 7;
    int mt_lin = lt >> 3;
    int e, start, nt;
    if (!decode_tile(counts, mt_lin, e, start, nt)) return;

    int tid = threadIdx.x;
    int w = tid >> 6, lane = tid & 63;
    int m16 = lane & 15, quad = lane >> 4;
    int wm = w & 1, wn = w >> 1;

    __shared__ unsigned short As[128][64];
    __shared__ unsigned short Bs[128][64];
    __shared__ int tokL[128];

    if (tid < 128)
        tokL[tid] = (tid < nt) ? btok[start + tid] : btok[start];
    __syncthreads();

    const unsigned short* WoE = Wob + (size_t)e * DIM * RR;

    const unsigned short* aS[4];
    const unsigned short* bS[4];
    int dstOff[4];
#pragma unroll
    for (int i = 0; i < 4; ++i) {
        int chunk = w * 4 + i;
        int row = chunk * 8 + (lane >> 3);
        int js  = (lane & 7) ^ (row & 7);
        aS[i] = Sbuf + (size_t)(start + row) * RR + js * 8;
        bS[i] = WoE + (size_t)(nd * 128 + row) * RR + js * 8;
        dstOff[i] = chunk * 1024;
    }
    auto* asb = (__attribute__((address_space(3))) char*)&As[0][0];
    auto* bsb = (__attribute__((address_space(3))) char*)&Bs[0][0];
    const char* Ab = (const char*)&As[0][0];
    const char* Bb = (const char*)&Bs[0][0];

    f32x4 acc[4][4];
    f32x4 zz = {0.f, 0.f, 0.f, 0.f};
#pragma unroll
    for (int mt = 0; mt < 4; ++mt)
#pragma unroll
        for (int nl = 0; nl < 4; ++nl) acc[mt][nl] = zz;

    for (int kt = 0; kt < 4; ++kt) {
        if (kt) __syncthreads();
#pragma unroll
        for (int i = 0; i < 4; ++i) {
            GLD16(aS[i] + kt * 64, asb + dstOff[i]);
            GLD16(bS[i] + kt * 64, bsb + dstOff[i]);
        }
        __syncthreads();
#pragma unroll
        for (int ks = 0; ks < 2; ++ks) {
            bf16x8 a[4], b[4];
#pragma unroll
            for (int mt = 0; mt < 4; ++mt) {
                int r = wm * 64 + mt * 16 + m16;
                int u = (ks * 4 + quad) ^ (r & 7);
                a[mt] = *(const bf16x8*)(Ab + r * 128 + u * 16);
            }
#pragma unroll
            for (int nl = 0; nl < 4; ++nl) {
                int r = wn * 64 + nl * 16 + m16;
                int u = (ks * 4 + quad) ^ (r & 7);
                b[nl] = *(const bf16x8*)(Bb + r * 128 + u * 16);
            }
#pragma unroll
            for (int nl = 0; nl < 4; ++nl)
#pragma unroll
                for (int mt = 0; mt < 4; ++mt)
                    acc[mt][nl] = __builtin_amdgcn_mfma_f32_16x16x32_bf16(a[mt], b[nl], acc[mt][nl], 0, 0, 0);
        }
    }

    if (ybuf) {
#pragma unroll
        for (int mt = 0; mt < 4; ++mt)
#pragma unroll
            for (int nl = 0; nl < 4; ++nl)
#pragma unroll
                for (int reg = 0; reg < 4; ++reg) {
                    int srow = wm * 64 + mt * 16 + quad * 4 + reg;
                    int d    = nd * 128 + wn * 64 + nl * 16 + m16;
                    if (srow < nt)
                        ybuf[(size_t)(start + srow) * DIM + d] = acc[mt][nl][reg];
                }
    } else {
#pragma unroll
        for (int mt = 0; mt < 4; ++mt)
#pragma unroll
            for (int nl = 0; nl < 4; ++nl)
#pragma unroll
                for (int reg = 0; reg < 4; ++reg) {
                    int srow = wm * 64 + mt * 16 + quad * 4 + reg;
                    int d    = nd * 128 + wn * 64 + nl * 16 + m16;
                    if (srow < nt)
                        atomicAdd(&out[(size_t)tokL[srow] * DIM + d], acc[mt][nl][reg]);
                }
    }
}

// ---------------- combine: out[t] = ybuf[slot0] + ybuf[slot1] ----------------
__global__ __launch_bounds__(256) void k_combine(const float* __restrict__ ybuf,
                                                 const int* __restrict__ slotOf,
                                                 float* __restrict__ out) {
    int t   = blockIdx.x;
    int seg = threadIdx.x;
    int s0 = slotOf[t * 2 + 0];
    int s1 = slotOf[t * 2 + 1];
    float4 a = *(const float4*)(ybuf + (size_t)s0 * DIM + seg * 4);
    float4 b = *(const float4*)(ybuf + (size_t)s1 * DIM + seg * 4);
    float4 r = { a.x + b.x, a.y + b.y, a.z + b.z, a.w + b.w };
    *(float4*)(out + (size_t)t * DIM + seg * 4) = r;
}

extern "C" void kernel_launch(void* const* d_in, const int* in_sizes, int n_in,
                              void* d_out, int out_size, void* d_ws, size_t ws_size,
                              hipStream_t stream) {
    const float* x  = (const float*)d_in[0];
    const float* gw = (const float*)d_in[1];
    const float* Wu = (const float*)d_in[2];
    const float* Wv = (const float*)d_in[3];
    const float* Wo = (const float*)d_in[4];
    float* out = (float*)d_out;

    int*   wsi     = (int*)d_ws;
    int*   counts  = wsi + 0;
    int*   fill    = wsi + 16;
    int*   topi    = wsi + 48;
    float* topw    = (float*)(wsi + 48 + 16384);
    int*   btok    = wsi + 48 + 32768;
    float* bw      = (float*)(wsi + 48 + 49152);
    int*   slotOf  = wsi + 48 + 65536;
    // routing region ends at byte 4*(48+81920) = 327,872
    float* gwT     = (float*)((char*)d_ws + 327872);              // 32 KB

    const size_t off_xb  = 393216;                                // 384 KB
    const size_t off_wub = off_xb  + (size_t)BN * DIM * 2;        // +16.78 MB
    const size_t off_wvb = off_wub + (size_t)NE * RR * DIM * 2;   // +4 MB
    const size_t off_wob = off_wvb + (size_t)NE * RR * DIM * 2;   // +4 MB
    const size_t off_sb  = off_wob + (size_t)NE * DIM * RR * 2;   // +4 MB
    const size_t off_yb  = off_sb  + (size_t)(BN * 2 + 128) * RR * 2; // +8.45 MB
    const size_t need_yb = off_yb  + (size_t)BN * 2 * DIM * 4;    // +67 MB ≈ 105 MB

    unsigned short* xb   = (unsigned short*)((char*)d_ws + off_xb);
    unsigned short* Wub  = (unsigned short*)((char*)d_ws + off_wub);
    unsigned short* Wvb  = (unsigned short*)((char*)d_ws + off_wvb);
    unsigned short* Wob  = (unsigned short*)((char*)d_ws + off_wob);
    unsigned short* Sbuf = (unsigned short*)((char*)d_ws + off_sb);
    bool use_ybuf = (ws_size >= need_yb);
    float* ybuf = use_ybuf ? (float*)((char*)d_ws + off_yb) : nullptr;

    // zero counts/fill (48 ints incl. padding)
    hipMemsetAsync(wsi, 0, 192, stream);

    k_gwt<<<dim3(DIM * NE / 256), 256, 0, stream>>>(gw, gwT);
    k_router3<<<dim3(BN / 4), 256, 0, stream>>>(x, gwT, topi, topw, xb, counts);
    k_fill2<<<dim3(BN * 2 / 256), 256, 0, stream>>>(topi, topw, counts, fill,
                                                    btok, bw, slotOf);
    k_cvt3<<<dim3(256, 24), 256, 0, stream>>>(Wu, Wv, Wo, Wub, Wvb, Wob);

    if (!use_ybuf)
        hipMemsetAsync(d_out, 0, (size_t)BN * DIM * sizeof(float), stream);

    k_uv<<<dim3(544), 256, 0, stream>>>(xb, Wub, Wvb, counts, btok, bw, Sbuf);
    k_down<<<dim3(1088), 256, 0, stream>>>(Sbuf, Wob, counts, btok, ybuf, out);
    if (use_ybuf)
        k_combine<<<dim3(BN), 256, 0, stream>>>(ybuf, slotOf, out);
}

// Round 9
// 190.180 us; speedup vs baseline: 1.0862x; 1.0393x over previous
//
#include <hip/hip_runtime.h>
#include <math.h>

#define BN 8192      // B*N tokens
#define DIM 1024     // D
#define NE 8         // E experts
#define RR 256       // R

using bf16x8 = __attribute__((ext_vector_type(8))) short;
using f32x4  = __attribute__((ext_vector_type(4))) float;

#define GLD16(g, l) __builtin_amdgcn_global_load_lds(                      \
    (const __attribute__((address_space(1))) void*)(g),                    \
    (__attribute__((address_space(3))) void*)(l), 16, 0, 0)

__device__ inline unsigned short f2bf(float f) {
    unsigned int u = __float_as_uint(f);
    u = (u + 0x7fffu + ((u >> 16) & 1u)) >> 16;
    return (unsigned short)u;
}
__device__ inline float bf2f(unsigned short h) {
    unsigned int u = ((unsigned int)h) << 16;
    return __uint_as_float(u);
}

// ---------------- gw transpose: [D][E] -> [E][D] fp32 ----------------
// Coalesced gwT reads in the router are worth far more than this launch:
// native-layout gw reads put lanes 128B apart (64-line replay per load).
__global__ __launch_bounds__(256) void k_gwt(const float* __restrict__ gw,
                                             float* __restrict__ gwT) {
    int i = blockIdx.x * 256 + threadIdx.x;
    float v = gw[i];
    int d = i >> 3, e = i & 7;
    gwT[e * DIM + d] = v;
}

// ------- routing (coalesced gwT) + x->bf16 + per-block counting -------------
__global__ __launch_bounds__(256) void k_router3(const float* __restrict__ x,
                                                 const float* __restrict__ gwT,
                                                 int* __restrict__ topi,
                                                 float* __restrict__ topw,
                                                 unsigned short* __restrict__ xb,
                                                 int* __restrict__ counts) {
    int wid  = (blockIdx.x * blockDim.x + threadIdx.x) >> 6;
    int lane = threadIdx.x & 63;
    const float* xp = x + (size_t)wid * DIM + lane * 4;
    unsigned short* xbp = xb + (size_t)wid * DIM + lane * 4;

    // all x loads in flight first
    float4 xva[4];
#pragma unroll
    for (int k = 0; k < 4; ++k) xva[k] = *(const float4*)(xp + k * 256);

    float4 acc[NE];
#pragma unroll
    for (int e = 0; e < NE; ++e) acc[e] = float4{0.f, 0.f, 0.f, 0.f};
#pragma unroll
    for (int k = 0; k < 4; ++k) {
        float4 xv = xva[k];
#pragma unroll
        for (int e = 0; e < NE; ++e) {
            float4 gv = *(const float4*)(gwT + e * DIM + k * 256 + lane * 4);
            acc[e].x += xv.x * gv.x; acc[e].y += xv.y * gv.y;
            acc[e].z += xv.z * gv.z; acc[e].w += xv.w * gv.w;
        }
    }

    // bf16 conversion + stores last (no consumer)
#pragma unroll
    for (int k = 0; k < 4; ++k) {
        float4 xv = xva[k];
        ushort4 us = { f2bf(xv.x), f2bf(xv.y), f2bf(xv.z), f2bf(xv.w) };
        *(ushort4*)(xbp + k * 256) = us;
    }

    float lg[NE];
#pragma unroll
    for (int e = 0; e < NE; ++e)
        lg[e] = (acc[e].x + acc[e].y) + (acc[e].z + acc[e].w);
#pragma unroll
    for (int off = 32; off; off >>= 1) {
#pragma unroll
        for (int e = 0; e < NE; ++e) lg[e] += __shfl_xor(lg[e], off, 64);
    }
    __shared__ int bc[NE];
    if (threadIdx.x < NE) bc[threadIdx.x] = 0;
    __syncthreads();
    if (lane == 0) {
        float best = lg[0]; int bi = 0;
#pragma unroll
        for (int e = 1; e < NE; ++e) if (lg[e] > best) { best = lg[e]; bi = e; }
        float sec = -3.4e38f; int si = 0;
#pragma unroll
        for (int e = 0; e < NE; ++e) if (e != bi && lg[e] > sec) { sec = lg[e]; si = e; }
        float p  = __expf(sec - best);
        float w0 = 1.f / (1.f + p);
        float w1 = p * w0;
        topi[wid * 2 + 0] = bi;  topw[wid * 2 + 0] = w0;
        topi[wid * 2 + 1] = si;  topw[wid * 2 + 1] = w1;
        atomicAdd(&bc[bi], 1);
        atomicAdd(&bc[si], 1);
    }
    __syncthreads();
    if (threadIdx.x < NE) {
        int c = bc[threadIdx.x];
        if (c) atomicAdd(&counts[threadIdx.x], c);
    }
}

// ---------------- bucket fill: offsets computed in-block from counts --------
__global__ __launch_bounds__(256) void k_fill2(const int* __restrict__ topi,
                                               const float* __restrict__ topw,
                                               const int* __restrict__ counts,
                                               int* __restrict__ fill,
                                               int* __restrict__ btok,
                                               float* __restrict__ bw,
                                               int* __restrict__ slotOf) {
    int tid = threadIdx.x;
    int i = blockIdx.x * 256 + tid;
    int w = tid >> 6, lane = tid & 63;
    int e = topi[i];
    float wt = topw[i];

    __shared__ int waveCnt[4][NE];
    __shared__ int wavePre[4][NE];
    __shared__ int baseSh[NE];
    __shared__ int offSh[NE];

    int myrank = 0;
    unsigned long long lt = (1ull << lane) - 1ull;
#pragma unroll
    for (int j = 0; j < NE; ++j) {
        unsigned long long m = __ballot(e == j);
        if (e == j) myrank = __popcll(m & lt);
        if (lane == 0) waveCnt[w][j] = __popcll(m);
    }
    if (tid == 0) {
        int acc = 0;
#pragma unroll
        for (int j = 0; j < NE; ++j) { offSh[j] = acc; acc += counts[j]; }
    }
    __syncthreads();
    if (tid < NE) {
        int j = tid, acc = 0;
#pragma unroll
        for (int ww = 0; ww < 4; ++ww) { wavePre[ww][j] = acc; acc += waveCnt[ww][j]; }
        baseSh[j] = atomicAdd(&fill[j], acc);
    }
    __syncthreads();
    int slot = offSh[e] + baseSh[e] + wavePre[w][e] + myrank;
    btok[slot] = i >> 1;
    bw[slot]   = wt;
    slotOf[i]  = slot;
}

// -------- fused weight transpose+convert: 3 tensors, one launch -------------
__global__ __launch_bounds__(256) void k_cvt3(const float* __restrict__ Wu,
                                              const float* __restrict__ Wv,
                                              const float* __restrict__ Wo,
                                              unsigned short* __restrict__ Wub,
                                              unsigned short* __restrict__ Wvb,
                                              unsigned short* __restrict__ Wob) {
    int z = blockIdx.y;
    int which = z >> 3, e = z & 7;
    int tile = blockIdx.x;
    const float* in; unsigned short* out;
    int M, N, n0, m0;
    if (which < 2) {
        M = DIM; N = RR;
        n0 = (tile & 7) * 32;  m0 = (tile >> 3) * 32;
        in = which ? Wv : Wu;  out = which ? Wvb : Wub;
    } else {
        M = RR; N = DIM;
        n0 = (tile & 31) * 32; m0 = (tile >> 5) * 32;
        in = Wo; out = Wob;
    }
    __shared__ float t[32][33];
    int tx = threadIdx.x & 31, ty = threadIdx.x >> 5;
    const float* inE = in + (size_t)e * M * N;
    unsigned short* outE = out + (size_t)e * M * N;
#pragma unroll
    for (int i = ty; i < 32; i += 8)
        t[i][tx] = inE[(size_t)(m0 + i) * N + n0 + tx];
    __syncthreads();
#pragma unroll
    for (int i = ty; i < 32; i += 8)
        outE[(size_t)(n0 + i) * M + m0 + tx] = f2bf(t[tx][i]);
}

// -------- inline tile decode from counts (replaces offsets/tileOff) ---------
__device__ inline bool decode_tile(const int* __restrict__ counts, int mt_lin,
                                   int& e, int& start, int& nt) {
    int acc = 0, tacc = 0;
    e = -1;
    int t0 = 0, ne = 0;
#pragma unroll
    for (int j = 0; j < NE; ++j) {
        int cj = counts[j];
        int tj = (cj + 127) >> 7;
        if (e < 0 && mt_lin < tacc + tj) {
            e = j; t0 = (mt_lin - tacc) * 128; start = acc + t0; ne = cj;
        }
        tacc += tj; acc += cj;
    }
    if (e < 0) return false;
    nt = min(128, ne - t0);
    return true;
}

// ---------------- UV kernel: S = silu(X Wu)*(X Wv)*gate ---------------------
// Round-3 proven config: single-buffered m97-style 128x128 tile, ~33 KB LDS,
// __launch_bounds__(256,2) (4 blocks/CU fit by LDS; cross-block TLP hides
// the per-kt vmcnt(0)+barrier drain). XOR-swizzled staging (rule #21).
// Grid 544 = 8*68, XCD-chunked: lt = (bid&7)*68 + bid>>3.
__global__ __launch_bounds__(256, 2) void k_uv(
        const unsigned short* __restrict__ xb,
        const unsigned short* __restrict__ Wub,   // [E][R][D] k-contig
        const unsigned short* __restrict__ Wvb,
        const int* __restrict__ counts,
        const int* __restrict__ btok,
        const float* __restrict__ bw,
        unsigned short* __restrict__ Sbuf) {
    int bid = blockIdx.x;
    int lt  = (bid & 7) * 68 + (bid >> 3);   // bijective: 544 = 8*68
    int rt  = lt & 3;
    int mt_lin = lt >> 2;
    int e, start, nt;
    if (!decode_tile(counts, mt_lin, e, start, nt)) return;

    int tid = threadIdx.x;
    int w = tid >> 6, lane = tid & 63;
    int m16 = lane & 15, quad = lane >> 4;
    int wm = w & 1, wn = w >> 1;

    __shared__ unsigned short As[128][64];
    __shared__ unsigned short Bs[128][64];
    __shared__ int   tokL[128];
    __shared__ float gwL[128];

    if (tid < 128) {
        tokL[tid] = (tid < nt) ? btok[start + tid] : btok[start];
        gwL[tid]  = (tid < nt) ? bw[start + tid] : 0.f;
    }
    __syncthreads();

    int rc0 = rt * 64;
    const unsigned short* WuE = Wub + (size_t)e * RR * DIM;
    const unsigned short* WvE = Wvb + (size_t)e * RR * DIM;

    // staging descriptors: chunk c = w*4+i covers LDS rows [c*8, c*8+8);
    // lane covers row c*8 + lane/8, 16B unit j = lane&7, stored linearly;
    // global source pre-swizzled: unit js = j ^ (row&7)  (rule #21)
    const unsigned short* aS[4];
    const unsigned short* bS[4];
    int dstOff[4];
#pragma unroll
    for (int i = 0; i < 4; ++i) {
        int chunk = w * 4 + i;
        int row = chunk * 8 + (lane >> 3);
        int js  = (lane & 7) ^ (row & 7);
        aS[i] = xb + (size_t)tokL[row] * DIM + js * 8;
        bS[i] = ((row < 64) ? (WuE + (size_t)(rc0 + row) * DIM)
                            : (WvE + (size_t)(rc0 + row - 64) * DIM)) + js * 8;
        dstOff[i] = chunk * 1024;
    }
    auto* asb = (__attribute__((address_space(3))) char*)&As[0][0];
    auto* bsb = (__attribute__((address_space(3))) char*)&Bs[0][0];
    const char* Ab = (const char*)&As[0][0];
    const char* Bb = (const char*)&Bs[0][0];

    f32x4 accU[4][2], accV[4][2];
    f32x4 zz = {0.f, 0.f, 0.f, 0.f};
#pragma unroll
    for (int mt = 0; mt < 4; ++mt)
#pragma unroll
        for (int nl = 0; nl < 2; ++nl) { accU[mt][nl] = zz; accV[mt][nl] = zz; }

    for (int kt = 0; kt < 16; ++kt) {
        if (kt) __syncthreads();
#pragma unroll
        for (int i = 0; i < 4; ++i) {
            GLD16(aS[i] + kt * 64, asb + dstOff[i]);
            GLD16(bS[i] + kt * 64, bsb + dstOff[i]);
        }
        __syncthreads();
#pragma unroll
        for (int ks = 0; ks < 2; ++ks) {
            bf16x8 a[4], bu[2], bv[2];
#pragma unroll
            for (int mt = 0; mt < 4; ++mt) {
                int r = wm * 64 + mt * 16 + m16;
                int u = (ks * 4 + quad) ^ (r & 7);
                a[mt] = *(const bf16x8*)(Ab + r * 128 + u * 16);
            }
#pragma unroll
            for (int nl = 0; nl < 2; ++nl) {
                int r = wn * 32 + nl * 16 + m16;
                int u = (ks * 4 + quad) ^ (r & 7);
                bu[nl] = *(const bf16x8*)(Bb + r * 128 + u * 16);
                bv[nl] = *(const bf16x8*)(Bb + (r + 64) * 128 + u * 16);
            }
#pragma unroll
            for (int nl = 0; nl < 2; ++nl)
#pragma unroll
                for (int mt = 0; mt < 4; ++mt) {
                    accU[mt][nl] = __builtin_amdgcn_mfma_f32_16x16x32_bf16(a[mt], bu[nl], accU[mt][nl], 0, 0, 0);
                    accV[mt][nl] = __builtin_amdgcn_mfma_f32_16x16x32_bf16(a[mt], bv[nl], accV[mt][nl], 0, 0, 0);
                }
        }
    }

#pragma unroll
    for (int mt = 0; mt < 4; ++mt)
#pragma unroll
        for (int nl = 0; nl < 2; ++nl)
#pragma unroll
            for (int reg = 0; reg < 4; ++reg) {
                int trow = wm * 64 + mt * 16 + quad * 4 + reg;
                int rcol = rc0 + wn * 32 + nl * 16 + m16;
                float u = accU[mt][nl][reg], v = accV[mt][nl][reg];
                float s = (u / (1.f + __expf(-u))) * v * gwL[trow];
                if (trow < nt)
                    Sbuf[(size_t)(start + trow) * RR + rcol] = f2bf(s);
            }
}

// ---------------- down-proj: ybuf[slot] = S * WoT (no atomics) --------------
// Round-3 proven config; ybuf stored as BF16 (halves ybuf write + combine
// read traffic; accumulation stays fp32, only the per-expert y is rounded).
// Grid 1088 = 8*136: lt = (bid&7)*136 + bid>>3; nd = lt&7, mt_lin = lt>>3.
__global__ __launch_bounds__(256, 2) void k_down(
        const unsigned short* __restrict__ Sbuf,
        const unsigned short* __restrict__ Wob,   // [E][D][R] k-contig
        const int* __restrict__ counts,
        const int* __restrict__ btok,
        unsigned short* __restrict__ ybuf,        // [slots][D] bf16, or null
        float* __restrict__ out) {
    int bid = blockIdx.x;
    int lt  = (bid & 7) * 136 + (bid >> 3);  // bijective: 1088 = 8*136
    int nd = lt & 7;
    int mt_lin = lt >> 3;
    int e, start, nt;
    if (!decode_tile(counts, mt_lin, e, start, nt)) return;

    int tid = threadIdx.x;
    int w = tid >> 6, lane = tid & 63;
    int m16 = lane & 15, quad = lane >> 4;
    int wm = w & 1, wn = w >> 1;

    __shared__ unsigned short As[128][64];
    __shared__ unsigned short Bs[128][64];
    __shared__ int tokL[128];

    if (tid < 128)
        tokL[tid] = (tid < nt) ? btok[start + tid] : btok[start];
    __syncthreads();

    const unsigned short* WoE = Wob + (size_t)e * DIM * RR;

    const unsigned short* aS[4];
    const unsigned short* bS[4];
    int dstOff[4];
#pragma unroll
    for (int i = 0; i < 4; ++i) {
        int chunk = w * 4 + i;
        int row = chunk * 8 + (lane >> 3);
        int js  = (lane & 7) ^ (row & 7);
        aS[i] = Sbuf + (size_t)(start + row) * RR + js * 8;
        bS[i] = WoE + (size_t)(nd * 128 + row) * RR + js * 8;
        dstOff[i] = chunk * 1024;
    }
    auto* asb = (__attribute__((address_space(3))) char*)&As[0][0];
    auto* bsb = (__attribute__((address_space(3))) char*)&Bs[0][0];
    const char* Ab = (const char*)&As[0][0];
    const char* Bb = (const char*)&Bs[0][0];

    f32x4 acc[4][4];
    f32x4 zz = {0.f, 0.f, 0.f, 0.f};
#pragma unroll
    for (int mt = 0; mt < 4; ++mt)
#pragma unroll
        for (int nl = 0; nl < 4; ++nl) acc[mt][nl] = zz;

    for (int kt = 0; kt < 4; ++kt) {
        if (kt) __syncthreads();
#pragma unroll
        for (int i = 0; i < 4; ++i) {
            GLD16(aS[i] + kt * 64, asb + dstOff[i]);
            GLD16(bS[i] + kt * 64, bsb + dstOff[i]);
        }
        __syncthreads();
#pragma unroll
        for (int ks = 0; ks < 2; ++ks) {
            bf16x8 a[4], b[4];
#pragma unroll
            for (int mt = 0; mt < 4; ++mt) {
                int r = wm * 64 + mt * 16 + m16;
                int u = (ks * 4 + quad) ^ (r & 7);
                a[mt] = *(const bf16x8*)(Ab + r * 128 + u * 16);
            }
#pragma unroll
            for (int nl = 0; nl < 4; ++nl) {
                int r = wn * 64 + nl * 16 + m16;
                int u = (ks * 4 + quad) ^ (r & 7);
                b[nl] = *(const bf16x8*)(Bb + r * 128 + u * 16);
            }
#pragma unroll
            for (int nl = 0; nl < 4; ++nl)
#pragma unroll
                for (int mt = 0; mt < 4; ++mt)
                    acc[mt][nl] = __builtin_amdgcn_mfma_f32_16x16x32_bf16(a[mt], b[nl], acc[mt][nl], 0, 0, 0);
        }
    }

    if (ybuf) {
#pragma unroll
        for (int mt = 0; mt < 4; ++mt)
#pragma unroll
            for (int nl = 0; nl < 4; ++nl)
#pragma unroll
                for (int reg = 0; reg < 4; ++reg) {
                    int srow = wm * 64 + mt * 16 + quad * 4 + reg;
                    int d    = nd * 128 + wn * 64 + nl * 16 + m16;
                    if (srow < nt)
                        ybuf[(size_t)(start + srow) * DIM + d] = f2bf(acc[mt][nl][reg]);
                }
    } else {
#pragma unroll
        for (int mt = 0; mt < 4; ++mt)
#pragma unroll
            for (int nl = 0; nl < 4; ++nl)
#pragma unroll
                for (int reg = 0; reg < 4; ++reg) {
                    int srow = wm * 64 + mt * 16 + quad * 4 + reg;
                    int d    = nd * 128 + wn * 64 + nl * 16 + m16;
                    if (srow < nt)
                        atomicAdd(&out[(size_t)tokL[srow] * DIM + d], acc[mt][nl][reg]);
                }
    }
}

// ---------------- combine: out[t] = ybuf[slot0] + ybuf[slot1] (bf16 in) -----
__global__ __launch_bounds__(256) void k_combine(const unsigned short* __restrict__ ybuf,
                                                 const int* __restrict__ slotOf,
                                                 float* __restrict__ out) {
    int t   = blockIdx.x;
    int seg = threadIdx.x;
    int s0 = slotOf[t * 2 + 0];
    int s1 = slotOf[t * 2 + 1];
    ushort4 a4 = *(const ushort4*)(ybuf + (size_t)s0 * DIM + seg * 4);
    ushort4 b4 = *(const ushort4*)(ybuf + (size_t)s1 * DIM + seg * 4);
    float4 r = { bf2f(a4.x) + bf2f(b4.x), bf2f(a4.y) + bf2f(b4.y),
                 bf2f(a4.z) + bf2f(b4.z), bf2f(a4.w) + bf2f(b4.w) };
    *(float4*)(out + (size_t)t * DIM + seg * 4) = r;
}

extern "C" void kernel_launch(void* const* d_in, const int* in_sizes, int n_in,
                              void* d_out, int out_size, void* d_ws, size_t ws_size,
                              hipStream_t stream) {
    const float* x  = (const float*)d_in[0];
    const float* gw = (const float*)d_in[1];
    const float* Wu = (const float*)d_in[2];
    const float* Wv = (const float*)d_in[3];
    const float* Wo = (const float*)d_in[4];
    float* out = (float*)d_out;

    int*   wsi     = (int*)d_ws;
    int*   counts  = wsi + 0;
    int*   fill    = wsi + 16;
    int*   topi    = wsi + 48;
    float* topw    = (float*)(wsi + 48 + 16384);
    int*   btok    = wsi + 48 + 32768;
    float* bw      = (float*)(wsi + 48 + 49152);
    int*   slotOf  = wsi + 48 + 65536;
    // routing region ends at byte 4*(48+81920) = 327,872
    float* gwT     = (float*)((char*)d_ws + 327872);              // 32 KB

    const size_t off_xb  = 393216;                                // 384 KB
    const size_t off_wub = off_xb  + (size_t)BN * DIM * 2;        // +16.78 MB
    const size_t off_wvb = off_wub + (size_t)NE * RR * DIM * 2;   // +4 MB
    const size_t off_wob = off_wvb + (size_t)NE * RR * DIM * 2;   // +4 MB
    const size_t off_sb  = off_wob + (size_t)NE * DIM * RR * 2;   // +4 MB
    const size_t off_yb  = off_sb  + (size_t)(BN * 2 + 128) * RR * 2; // +8.45 MB
    const size_t need_yb = off_yb  + (size_t)BN * 2 * DIM * 2;    // bf16 ybuf ≈ 33.5 MB

    unsigned short* xb   = (unsigned short*)((char*)d_ws + off_xb);
    unsigned short* Wub  = (unsigned short*)((char*)d_ws + off_wub);
    unsigned short* Wvb  = (unsigned short*)((char*)d_ws + off_wvb);
    unsigned short* Wob  = (unsigned short*)((char*)d_ws + off_wob);
    unsigned short* Sbuf = (unsigned short*)((char*)d_ws + off_sb);
    bool use_ybuf = (ws_size >= need_yb);
    unsigned short* ybuf = use_ybuf ? (unsigned short*)((char*)d_ws + off_yb) : nullptr;

    // zero counts/fill (48 ints incl. padding)
    hipMemsetAsync(wsi, 0, 192, stream);

    k_gwt<<<dim3(DIM * NE / 256), 256, 0, stream>>>(gw, gwT);
    k_router3<<<dim3(BN / 4), 256, 0, stream>>>(x, gwT, topi, topw, xb, counts);
    k_fill2<<<dim3(BN * 2 / 256), 256, 0, stream>>>(topi, topw, counts, fill,
                                                    btok, bw, slotOf);
    k_cvt3<<<dim3(256, 24), 256, 0, stream>>>(Wu, Wv, Wo, Wub, Wvb, Wob);

    if (!use_ybuf)
        hipMemsetAsync(d_out, 0, (size_t)BN * DIM * sizeof(float), stream);

    k_uv<<<dim3(544), 256, 0, stream>>>(xb, Wub, Wvb, counts, btok, bw, Sbuf);
    k_down<<<dim3(1088), 256, 0, stream>>>(Sbuf, Wob, counts, btok, ybuf, out);
    if (use_ybuf)
        k_combine<<<dim3(BN), 256, 0, stream>>>(ybuf, slotOf, out);
}

// Round 10
// 189.344 us; speedup vs baseline: 1.0909x; 1.0044x over previous
//
#include <hip/hip_runtime.h>
#include <math.h>

#define BN 8192      // B*N tokens
#define DIM 1024     // D
#define NE 8         // E experts
#define RR 256       // R

using bf16x8 = __attribute__((ext_vector_type(8))) short;
using f32x4  = __attribute__((ext_vector_type(4))) float;

#define GLD16(g, l) __builtin_amdgcn_global_load_lds(                      \
    (const __attribute__((address_space(1))) void*)(g),                    \
    (__attribute__((address_space(3))) void*)(l), 16, 0, 0)

__device__ inline unsigned short f2bf(float f) {
    unsigned int u = __float_as_uint(f);
    u = (u + 0x7fffu + ((u >> 16) & 1u)) >> 16;
    return (unsigned short)u;
}
__device__ inline float bf2f(unsigned short h) {
    unsigned int u = ((unsigned int)h) << 16;
    return __uint_as_float(u);
}

// ------- routing: gwT staged in LDS once per block + x->bf16 + counting -----
// Each wave previously streamed the whole 32 KB gwT from L2 (268 MB total,
// 32 serially-latent loads/thread). Stage it in LDS once per block; the 32
// gate loads become conflict-free ds_read_b128.
__global__ __launch_bounds__(256) void k_router3(const float* __restrict__ x,
                                                 const float* __restrict__ gwT,
                                                 int* __restrict__ topi,
                                                 float* __restrict__ topw,
                                                 unsigned short* __restrict__ xb,
                                                 int* __restrict__ counts) {
    __shared__ float gws[NE * DIM];   // 32 KB
    __shared__ int bc[NE];
    int tid = threadIdx.x;
    {
        const float4* src = (const float4*)gwT;
        float4* dst = (float4*)gws;
#pragma unroll
        for (int i = 0; i < 8; ++i)
            dst[tid + i * 256] = src[tid + i * 256];
    }
    if (tid < NE) bc[tid] = 0;

    int wid  = (blockIdx.x * blockDim.x + tid) >> 6;
    int lane = tid & 63;
    const float* xp = x + (size_t)wid * DIM + lane * 4;
    unsigned short* xbp = xb + (size_t)wid * DIM + lane * 4;

    // all x loads in flight while LDS staging completes
    float4 xva[4];
#pragma unroll
    for (int k = 0; k < 4; ++k) xva[k] = *(const float4*)(xp + k * 256);

    __syncthreads();   // gws ready

    float4 acc[NE];
#pragma unroll
    for (int e = 0; e < NE; ++e) acc[e] = float4{0.f, 0.f, 0.f, 0.f};
#pragma unroll
    for (int k = 0; k < 4; ++k) {
        float4 xv = xva[k];
#pragma unroll
        for (int e = 0; e < NE; ++e) {
            float4 gv = *(const float4*)(gws + e * DIM + k * 256 + lane * 4);
            acc[e].x += xv.x * gv.x; acc[e].y += xv.y * gv.y;
            acc[e].z += xv.z * gv.z; acc[e].w += xv.w * gv.w;
        }
    }

    // bf16 conversion + stores last (no consumer)
#pragma unroll
    for (int k = 0; k < 4; ++k) {
        float4 xv = xva[k];
        ushort4 us = { f2bf(xv.x), f2bf(xv.y), f2bf(xv.z), f2bf(xv.w) };
        *(ushort4*)(xbp + k * 256) = us;
    }

    float lg[NE];
#pragma unroll
    for (int e = 0; e < NE; ++e)
        lg[e] = (acc[e].x + acc[e].y) + (acc[e].z + acc[e].w);
#pragma unroll
    for (int off = 32; off; off >>= 1) {
#pragma unroll
        for (int e = 0; e < NE; ++e) lg[e] += __shfl_xor(lg[e], off, 64);
    }
    if (lane == 0) {
        float best = lg[0]; int bi = 0;
#pragma unroll
        for (int e = 1; e < NE; ++e) if (lg[e] > best) { best = lg[e]; bi = e; }
        float sec = -3.4e38f; int si = 0;
#pragma unroll
        for (int e = 0; e < NE; ++e) if (e != bi && lg[e] > sec) { sec = lg[e]; si = e; }
        float p  = __expf(sec - best);
        float w0 = 1.f / (1.f + p);
        float w1 = p * w0;
        topi[wid * 2 + 0] = bi;  topw[wid * 2 + 0] = w0;
        topi[wid * 2 + 1] = si;  topw[wid * 2 + 1] = w1;
        atomicAdd(&bc[bi], 1);
        atomicAdd(&bc[si], 1);
    }
    __syncthreads();
    if (tid < NE) {
        int c = bc[tid];
        if (c) atomicAdd(&counts[tid], c);
    }
}

// ---------------- bucket fill: offsets computed in-block from counts --------
__global__ __launch_bounds__(256) void k_fill2(const int* __restrict__ topi,
                                               const float* __restrict__ topw,
                                               const int* __restrict__ counts,
                                               int* __restrict__ fill,
                                               int* __restrict__ btok,
                                               float* __restrict__ bw,
                                               int* __restrict__ slotOf) {
    int tid = threadIdx.x;
    int i = blockIdx.x * 256 + tid;
    int w = tid >> 6, lane = tid & 63;
    int e = topi[i];
    float wt = topw[i];

    __shared__ int waveCnt[4][NE];
    __shared__ int wavePre[4][NE];
    __shared__ int baseSh[NE];
    __shared__ int offSh[NE];

    int myrank = 0;
    unsigned long long lt = (1ull << lane) - 1ull;
#pragma unroll
    for (int j = 0; j < NE; ++j) {
        unsigned long long m = __ballot(e == j);
        if (e == j) myrank = __popcll(m & lt);
        if (lane == 0) waveCnt[w][j] = __popcll(m);
    }
    if (tid == 0) {
        int acc = 0;
#pragma unroll
        for (int j = 0; j < NE; ++j) { offSh[j] = acc; acc += counts[j]; }
    }
    __syncthreads();
    if (tid < NE) {
        int j = tid, acc = 0;
#pragma unroll
        for (int ww = 0; ww < 4; ++ww) { wavePre[ww][j] = acc; acc += waveCnt[ww][j]; }
        baseSh[j] = atomicAdd(&fill[j], acc);
    }
    __syncthreads();
    int slot = offSh[e] + baseSh[e] + wavePre[w][e] + myrank;
    btok[slot] = i >> 1;
    bw[slot]   = wt;
    slotOf[i]  = slot;
}

// -------- fused weight transpose+convert + gw transpose: one launch ---------
// z = 0..23: Wu/Wv/Wo tiles as before; z = 24: gw [D][E] -> gwT [E][D] fp32
// (32 active blocks; the rest exit immediately).
__global__ __launch_bounds__(256) void k_cvt3(const float* __restrict__ Wu,
                                              const float* __restrict__ Wv,
                                              const float* __restrict__ Wo,
                                              const float* __restrict__ gw,
                                              unsigned short* __restrict__ Wub,
                                              unsigned short* __restrict__ Wvb,
                                              unsigned short* __restrict__ Wob,
                                              float* __restrict__ gwT) {
    int z = blockIdx.y;
    int tile = blockIdx.x;
    if (z == 24) {
        if (tile < 32) {
            int i = tile * 256 + threadIdx.x;
            float v = gw[i];
            int d = i >> 3, e = i & 7;
            gwT[e * DIM + d] = v;
        }
        return;
    }
    int which = z >> 3, e = z & 7;
    const float* in; unsigned short* out;
    int M, N, n0, m0;
    if (which < 2) {
        M = DIM; N = RR;
        n0 = (tile & 7) * 32;  m0 = (tile >> 3) * 32;
        in = which ? Wv : Wu;  out = which ? Wvb : Wub;
    } else {
        M = RR; N = DIM;
        n0 = (tile & 31) * 32; m0 = (tile >> 5) * 32;
        in = Wo; out = Wob;
    }
    __shared__ float t[32][33];
    int tx = threadIdx.x & 31, ty = threadIdx.x >> 5;
    const float* inE = in + (size_t)e * M * N;
    unsigned short* outE = out + (size_t)e * M * N;
#pragma unroll
    for (int i = ty; i < 32; i += 8)
        t[i][tx] = inE[(size_t)(m0 + i) * N + n0 + tx];
    __syncthreads();
#pragma unroll
    for (int i = ty; i < 32; i += 8)
        outE[(size_t)(n0 + i) * M + m0 + tx] = f2bf(t[tx][i]);
}

// -------- inline tile decode from counts (replaces offsets/tileOff) ---------
__device__ inline bool decode_tile(const int* __restrict__ counts, int mt_lin,
                                   int& e, int& start, int& nt) {
    int acc = 0, tacc = 0;
    e = -1;
    int t0 = 0, ne = 0;
#pragma unroll
    for (int j = 0; j < NE; ++j) {
        int cj = counts[j];
        int tj = (cj + 127) >> 7;
        if (e < 0 && mt_lin < tacc + tj) {
            e = j; t0 = (mt_lin - tacc) * 128; start = acc + t0; ne = cj;
        }
        tacc += tj; acc += cj;
    }
    if (e < 0) return false;
    nt = min(128, ne - t0);
    return true;
}

// ---------------- UV kernel: S = silu(X Wu)*(X Wv)*gate ---------------------
// Round-3 proven config: single-buffered m97-style 128x128 tile, ~33 KB LDS,
// __launch_bounds__(256,2) (4 blocks/CU fit by LDS; cross-block TLP hides
// the per-kt vmcnt(0)+barrier drain). XOR-swizzled staging (rule #21).
// Grid 544 = 8*68, XCD-chunked: lt = (bid&7)*68 + bid>>3.
__global__ __launch_bounds__(256, 2) void k_uv(
        const unsigned short* __restrict__ xb,
        const unsigned short* __restrict__ Wub,   // [E][R][D] k-contig
        const unsigned short* __restrict__ Wvb,
        const int* __restrict__ counts,
        const int* __restrict__ btok,
        const float* __restrict__ bw,
        unsigned short* __restrict__ Sbuf) {
    int bid = blockIdx.x;
    int lt  = (bid & 7) * 68 + (bid >> 3);   // bijective: 544 = 8*68
    int rt  = lt & 3;
    int mt_lin = lt >> 2;
    int e, start, nt;
    if (!decode_tile(counts, mt_lin, e, start, nt)) return;

    int tid = threadIdx.x;
    int w = tid >> 6, lane = tid & 63;
    int m16 = lane & 15, quad = lane >> 4;
    int wm = w & 1, wn = w >> 1;

    __shared__ unsigned short As[128][64];
    __shared__ unsigned short Bs[128][64];
    __shared__ int   tokL[128];
    __shared__ float gwL[128];

    if (tid < 128) {
        tokL[tid] = (tid < nt) ? btok[start + tid] : btok[start];
        gwL[tid]  = (tid < nt) ? bw[start + tid] : 0.f;
    }
    __syncthreads();

    int rc0 = rt * 64;
    const unsigned short* WuE = Wub + (size_t)e * RR * DIM;
    const unsigned short* WvE = Wvb + (size_t)e * RR * DIM;

    // staging descriptors: chunk c = w*4+i covers LDS rows [c*8, c*8+8);
    // lane covers row c*8 + lane/8, 16B unit j = lane&7, stored linearly;
    // global source pre-swizzled: unit js = j ^ (row&7)  (rule #21)
    const unsigned short* aS[4];
    const unsigned short* bS[4];
    int dstOff[4];
#pragma unroll
    for (int i = 0; i < 4; ++i) {
        int chunk = w * 4 + i;
        int row = chunk * 8 + (lane >> 3);
        int js  = (lane & 7) ^ (row & 7);
        aS[i] = xb + (size_t)tokL[row] * DIM + js * 8;
        bS[i] = ((row < 64) ? (WuE + (size_t)(rc0 + row) * DIM)
                            : (WvE + (size_t)(rc0 + row - 64) * DIM)) + js * 8;
        dstOff[i] = chunk * 1024;
    }
    auto* asb = (__attribute__((address_space(3))) char*)&As[0][0];
    auto* bsb = (__attribute__((address_space(3))) char*)&Bs[0][0];
    const char* Ab = (const char*)&As[0][0];
    const char* Bb = (const char*)&Bs[0][0];

    f32x4 accU[4][2], accV[4][2];
    f32x4 zz = {0.f, 0.f, 0.f, 0.f};
#pragma unroll
    for (int mt = 0; mt < 4; ++mt)
#pragma unroll
        for (int nl = 0; nl < 2; ++nl) { accU[mt][nl] = zz; accV[mt][nl] = zz; }

    for (int kt = 0; kt < 16; ++kt) {
        if (kt) __syncthreads();
#pragma unroll
        for (int i = 0; i < 4; ++i) {
            GLD16(aS[i] + kt * 64, asb + dstOff[i]);
            GLD16(bS[i] + kt * 64, bsb + dstOff[i]);
        }
        __syncthreads();
#pragma unroll
        for (int ks = 0; ks < 2; ++ks) {
            bf16x8 a[4], bu[2], bv[2];
#pragma unroll
            for (int mt = 0; mt < 4; ++mt) {
                int r = wm * 64 + mt * 16 + m16;
                int u = (ks * 4 + quad) ^ (r & 7);
                a[mt] = *(const bf16x8*)(Ab + r * 128 + u * 16);
            }
#pragma unroll
            for (int nl = 0; nl < 2; ++nl) {
                int r = wn * 32 + nl * 16 + m16;
                int u = (ks * 4 + quad) ^ (r & 7);
                bu[nl] = *(const bf16x8*)(Bb + r * 128 + u * 16);
                bv[nl] = *(const bf16x8*)(Bb + (r + 64) * 128 + u * 16);
            }
#pragma unroll
            for (int nl = 0; nl < 2; ++nl)
#pragma unroll
                for (int mt = 0; mt < 4; ++mt) {
                    accU[mt][nl] = __builtin_amdgcn_mfma_f32_16x16x32_bf16(a[mt], bu[nl], accU[mt][nl], 0, 0, 0);
                    accV[mt][nl] = __builtin_amdgcn_mfma_f32_16x16x32_bf16(a[mt], bv[nl], accV[mt][nl], 0, 0, 0);
                }
        }
    }

#pragma unroll
    for (int mt = 0; mt < 4; ++mt)
#pragma unroll
        for (int nl = 0; nl < 2; ++nl)
#pragma unroll
            for (int reg = 0; reg < 4; ++reg) {
                int trow = wm * 64 + mt * 16 + quad * 4 + reg;
                int rcol = rc0 + wn * 32 + nl * 16 + m16;
                float u = accU[mt][nl][reg], v = accV[mt][nl][reg];
                float s = (u / (1.f + __expf(-u))) * v * gwL[trow];
                if (trow < nt)
                    Sbuf[(size_t)(start + trow) * RR + rcol] = f2bf(s);
            }
}

// ---------------- down-proj: ybuf[slot] = S * WoT (no atomics) --------------
// Round-3 proven config; ybuf stored as BF16 (halves ybuf write + combine
// read traffic; accumulation stays fp32, only the per-expert y is rounded).
// Grid 1088 = 8*136: lt = (bid&7)*136 + bid>>3; nd = lt&7, mt_lin = lt>>3.
__global__ __launch_bounds__(256, 2) void k_down(
        const unsigned short* __restrict__ Sbuf,
        const unsigned short* __restrict__ Wob,   // [E][D][R] k-contig
        const int* __restrict__ counts,
        const int* __restrict__ btok,
        unsigned short* __restrict__ ybuf,        // [slots][D] bf16, or null
        float* __restrict__ out) {
    int bid = blockIdx.x;
    int lt  = (bid & 7) * 136 + (bid >> 3);  // bijective: 1088 = 8*136
    int nd = lt & 7;
    int mt_lin = lt >> 3;
    int e, start, nt;
    if (!decode_tile(counts, mt_lin, e, start, nt)) return;

    int tid = threadIdx.x;
    int w = tid >> 6, lane = tid & 63;
    int m16 = lane & 15, quad = lane >> 4;
    int wm = w & 1, wn = w >> 1;

    __shared__ unsigned short As[128][64];
    __shared__ unsigned short Bs[128][64];
    __shared__ int tokL[128];

    if (tid < 128)
        tokL[tid] = (tid < nt) ? btok[start + tid] : btok[start];
    __syncthreads();

    const unsigned short* WoE = Wob + (size_t)e * DIM * RR;

    const unsigned short* aS[4];
    const unsigned short* bS[4];
    int dstOff[4];
#pragma unroll
    for (int i = 0; i < 4; ++i) {
        int chunk = w * 4 + i;
        int row = chunk * 8 + (lane >> 3);
        int js  = (lane & 7) ^ (row & 7);
        aS[i] = Sbuf + (size_t)(start + row) * RR + js * 8;
        bS[i] = WoE + (size_t)(nd * 128 + row) * RR + js * 8;
        dstOff[i] = chunk * 1024;
    }
    auto* asb = (__attribute__((address_space(3))) char*)&As[0][0];
    auto* bsb = (__attribute__((address_space(3))) char*)&Bs[0][0];
    const char* Ab = (const char*)&As[0][0];
    const char* Bb = (const char*)&Bs[0][0];

    f32x4 acc[4][4];
    f32x4 zz = {0.f, 0.f, 0.f, 0.f};
#pragma unroll
    for (int mt = 0; mt < 4; ++mt)
#pragma unroll
        for (int nl = 0; nl < 4; ++nl) acc[mt][nl] = zz;

    for (int kt = 0; kt < 4; ++kt) {
        if (kt) __syncthreads();
#pragma unroll
        for (int i = 0; i < 4; ++i) {
            GLD16(aS[i] + kt * 64, asb + dstOff[i]);
            GLD16(bS[i] + kt * 64, bsb + dstOff[i]);
        }
        __syncthreads();
#pragma unroll
        for (int ks = 0; ks < 2; ++ks) {
            bf16x8 a[4], b[4];
#pragma unroll
            for (int mt = 0; mt < 4; ++mt) {
                int r = wm * 64 + mt * 16 + m16;
                int u = (ks * 4 + quad) ^ (r & 7);
                a[mt] = *(const bf16x8*)(Ab + r * 128 + u * 16);
            }
#pragma unroll
            for (int nl = 0; nl < 4; ++nl) {
                int r = wn * 64 + nl * 16 + m16;
                int u = (ks * 4 + quad) ^ (r & 7);
                b[nl] = *(const bf16x8*)(Bb + r * 128 + u * 16);
            }
#pragma unroll
            for (int nl = 0; nl < 4; ++nl)
#pragma unroll
                for (int mt = 0; mt < 4; ++mt)
                    acc[mt][nl] = __builtin_amdgcn_mfma_f32_16x16x32_bf16(a[mt], b[nl], acc[mt][nl], 0, 0, 0);
        }
    }

    if (ybuf) {
#pragma unroll
        for (int mt = 0; mt < 4; ++mt)
#pragma unroll
            for (int nl = 0; nl < 4; ++nl)
#pragma unroll
                for (int reg = 0; reg < 4; ++reg) {
                    int srow = wm * 64 + mt * 16 + quad * 4 + reg;
                    int d    = nd * 128 + wn * 64 + nl * 16 + m16;
                    if (srow < nt)
                        ybuf[(size_t)(start + srow) * DIM + d] = f2bf(acc[mt][nl][reg]);
                }
    } else {
#pragma unroll
        for (int mt = 0; mt < 4; ++mt)
#pragma unroll
            for (int nl = 0; nl < 4; ++nl)
#pragma unroll
                for (int reg = 0; reg < 4; ++reg) {
                    int srow = wm * 64 + mt * 16 + quad * 4 + reg;
                    int d    = nd * 128 + wn * 64 + nl * 16 + m16;
                    if (srow < nt)
                        atomicAdd(&out[(size_t)tokL[srow] * DIM + d], acc[mt][nl][reg]);
                }
    }
}

// ---------------- combine: out[t] = ybuf[slot0] + ybuf[slot1] (bf16 in) -----
__global__ __launch_bounds__(256) void k_combine(const unsigned short* __restrict__ ybuf,
                                                 const int* __restrict__ slotOf,
                                                 float* __restrict__ out) {
    int t   = blockIdx.x;
    int seg = threadIdx.x;
    int s0 = slotOf[t * 2 + 0];
    int s1 = slotOf[t * 2 + 1];
    ushort4 a4 = *(const ushort4*)(ybuf + (size_t)s0 * DIM + seg * 4);
    ushort4 b4 = *(const ushort4*)(ybuf + (size_t)s1 * DIM + seg * 4);
    float4 r = { bf2f(a4.x) + bf2f(b4.x), bf2f(a4.y) + bf2f(b4.y),
                 bf2f(a4.z) + bf2f(b4.z), bf2f(a4.w) + bf2f(b4.w) };
    *(float4*)(out + (size_t)t * DIM + seg * 4) = r;
}

extern "C" void kernel_launch(void* const* d_in, const int* in_sizes, int n_in,
                              void* d_out, int out_size, void* d_ws, size_t ws_size,
                              hipStream_t stream) {
    const float* x  = (const float*)d_in[0];
    const float* gw = (const float*)d_in[1];
    const float* Wu = (const float*)d_in[2];
    const float* Wv = (const float*)d_in[3];
    const float* Wo = (const float*)d_in[4];
    float* out = (float*)d_out;

    int*   wsi     = (int*)d_ws;
    int*   counts  = wsi + 0;
    int*   fill    = wsi + 16;
    int*   topi    = wsi + 48;
    float* topw    = (float*)(wsi + 48 + 16384);
    int*   btok    = wsi + 48 + 32768;
    float* bw      = (float*)(wsi + 48 + 49152);
    int*   slotOf  = wsi + 48 + 65536;
    // routing region ends at byte 4*(48+81920) = 327,872
    float* gwT     = (float*)((char*)d_ws + 327872);              // 32 KB

    const size_t off_xb  = 393216;                                // 384 KB
    const size_t off_wub = off_xb  + (size_t)BN * DIM * 2;        // +16.78 MB
    const size_t off_wvb = off_wub + (size_t)NE * RR * DIM * 2;   // +4 MB
    const size_t off_wob = off_wvb + (size_t)NE * RR * DIM * 2;   // +4 MB
    const size_t off_sb  = off_wob + (size_t)NE * DIM * RR * 2;   // +4 MB
    const size_t off_yb  = off_sb  + (size_t)(BN * 2 + 128) * RR * 2; // +8.45 MB
    const size_t need_yb = off_yb  + (size_t)BN * 2 * DIM * 2;    // bf16 ybuf ≈ 33.5 MB

    unsigned short* xb   = (unsigned short*)((char*)d_ws + off_xb);
    unsigned short* Wub  = (unsigned short*)((char*)d_ws + off_wub);
    unsigned short* Wvb  = (unsigned short*)((char*)d_ws + off_wvb);
    unsigned short* Wob  = (unsigned short*)((char*)d_ws + off_wob);
    unsigned short* Sbuf = (unsigned short*)((char*)d_ws + off_sb);
    bool use_ybuf = (ws_size >= need_yb);
    unsigned short* ybuf = use_ybuf ? (unsigned short*)((char*)d_ws + off_yb) : nullptr;

    // zero counts/fill (48 ints incl. padding)
    hipMemsetAsync(wsi, 0, 192, stream);

    k_cvt3<<<dim3(256, 25), 256, 0, stream>>>(Wu, Wv, Wo, gw, Wub, Wvb, Wob, gwT);
    k_router3<<<dim3(BN / 4), 256, 0, stream>>>(x, gwT, topi, topw, xb, counts);
    k_fill2<<<dim3(BN * 2 / 256), 256, 0, stream>>>(topi, topw, counts, fill,
                                                    btok, bw, slotOf);

    if (!use_ybuf)
        hipMemsetAsync(d_out, 0, (size_t)BN * DIM * sizeof(float), stream);

    k_uv<<<dim3(544), 256, 0, stream>>>(xb, Wub, Wvb, counts, btok, bw, Sbuf);
    k_down<<<dim3(1088), 256, 0, stream>>>(Sbuf, Wob, counts, btok, ybuf, out);
    if (use_ybuf)
        k_combine<<<dim3(BN), 256, 0, stream>>>(ybuf, slotOf, out);
}